// Round 9
// baseline (491.035 us; speedup 1.0000x reference)
//
#include <hip/hip_runtime.h>
#include <stdint.h>

typedef short     bf16x8  __attribute__((ext_vector_type(8)));
typedef float     f32x4   __attribute__((ext_vector_type(4)));
typedef unsigned short u16x8 __attribute__((ext_vector_type(8)));
typedef unsigned short u16x4 __attribute__((ext_vector_type(4)));
typedef unsigned int   u32x4 __attribute__((ext_vector_type(4)));

__device__ __forceinline__ float bf2f(unsigned short u) {
    union { unsigned int i; float f; } v; v.i = ((unsigned int)u) << 16; return v.f;
}
__device__ __forceinline__ unsigned short f2bf(float f) {
    union { float f; unsigned int i; } v; v.f = f;
    unsigned int x = v.i;
    return (unsigned short)((x + 0x7fffu + ((x >> 16) & 1u)) >> 16);
}
__device__ __forceinline__ unsigned int cvtpk(float lo, float hi) {
    unsigned int r;
    asm("v_cvt_pk_bf16_f32 %0, %1, %2" : "=v"(r) : "v"(lo), "v"(hi));
    return r;
}

// ---------- 24->24 stride-2 conv step, LDS -> LDS, NHWC ----------
__device__ __forceinline__ void convs24(const unsigned short* __restrict__ in, int H,
                                        unsigned short* __restrict__ out, int OH,
                                        const float* __restrict__ w, const float* __restrict__ bias,
                                        const float* __restrict__ bng, const float* __restrict__ bnb,
                                        int t, int nthr)
{
    int total = OH * OH;
    for (int p = t; p < total; p += nthr) {
        int ow = p % OH, oh = p / OH;
        float acc[24];
        #pragma unroll
        for (int co = 0; co < 24; ++co) acc[co] = 0.f;
        int ih0 = 2 * oh - 1, iw0 = 2 * ow - 1;
        #pragma unroll 1
        for (int ky = 0; ky < 3; ++ky) {
            int ih = ih0 + ky; if (ih < 0) continue;
            #pragma unroll 1
            for (int kx = 0; kx < 3; ++kx) {
                int iw = iw0 + kx; if (iw < 0) continue;
                const unsigned short* pp = in + (ih * H + iw) * 24;
                u16x4 v[6];
                #pragma unroll
                for (int m = 0; m < 6; ++m) v[m] = *(const u16x4*)(pp + m * 4);
                float x[24];
                #pragma unroll
                for (int m = 0; m < 6; ++m)
                    #pragma unroll
                    for (int e = 0; e < 4; ++e) x[m * 4 + e] = bf2f(v[m][e]);
                int kb = ky * 3 + kx;
                #pragma unroll
                for (int ci = 0; ci < 24; ++ci) {
                    float xv = x[ci];
                    #pragma unroll
                    for (int co = 0; co < 24; ++co)
                        acc[co] += xv * w[co * 216 + ci * 9 + kb];
                }
            }
        }
        unsigned short* op = out + p * 24;
        u16x4 o[6];
        #pragma unroll
        for (int co = 0; co < 24; ++co) {
            float scale = bng[co] * 0.9999950000374997f;
            o[co >> 2][co & 3] = f2bf((acc[co] + bias[co]) * scale + bnb[co]);
        }
        #pragma unroll
        for (int m = 0; m < 6; ++m) *(u16x4*)(op + m * 4) = o[m];
    }
}

// ---------- fully fused conv1..conv4: one block per image; writes only Xf ----------
__global__ __launch_bounds__(1024) void conv_fused_kernel(
    const float* __restrict__ im,
    const float* __restrict__ c1w, const float* __restrict__ c1b,
    const float* __restrict__ n1g, const float* __restrict__ n1b,
    const float* __restrict__ c2w, const float* __restrict__ c2b,
    const float* __restrict__ n2g, const float* __restrict__ n2b,
    const float* __restrict__ c3w, const float* __restrict__ c3b,
    const float* __restrict__ n3g, const float* __restrict__ n3b,
    const float* __restrict__ c4w, const float* __restrict__ c4b,
    const float* __restrict__ n4g, const float* __restrict__ n4b,
    unsigned short* __restrict__ Xf)
{
    extern __shared__ unsigned short smem[];
    unsigned short* bufA = smem;            // 19200: im bf16; later c2 (9600)
    unsigned short* bufB = smem + 19200;    // 38400: c1; later c3 (2400)
    int b = blockIdx.x, t = threadIdx.x;

    // stage image (fp32 -> bf16, coalesced)
    const float* ip = im + (size_t)b * 19200;
    for (int i = t; i < 19200; i += 1024) bufA[i] = f2bf(ip[i]);
    __syncthreads();

    // conv1: bufA [3][80][80] -> bufB [40][40][24]
    for (int p = t; p < 1600; p += 1024) {
        int ow = p % 40, oh = p / 40;
        float acc[24];
        #pragma unroll
        for (int co = 0; co < 24; ++co) acc[co] = 0.f;
        int ih0 = 2 * oh - 1, iw0 = 2 * ow - 1;
        #pragma unroll 1
        for (int ci = 0; ci < 3; ++ci) {
            #pragma unroll 1
            for (int ky = 0; ky < 3; ++ky) {
                int ih = ih0 + ky; if (ih < 0) continue;
                #pragma unroll 1
                for (int kx = 0; kx < 3; ++kx) {
                    int iw = iw0 + kx; if (iw < 0) continue;
                    float x = bf2f(bufA[ci * 6400 + ih * 80 + iw]);
                    int k = ci * 9 + ky * 3 + kx;
                    #pragma unroll
                    for (int co = 0; co < 24; ++co) acc[co] += x * c1w[co * 27 + k];
                }
            }
        }
        unsigned short* op = bufB + p * 24;
        u16x4 o[6];
        #pragma unroll
        for (int co = 0; co < 24; ++co) {
            float scale = n1g[co] * 0.9999950000374997f;
            o[co >> 2][co & 3] = f2bf((acc[co] + c1b[co]) * scale + n1b[co]);
        }
        #pragma unroll
        for (int m = 0; m < 6; ++m) *(u16x4*)(op + m * 4) = o[m];
    }
    __syncthreads();

    // conv2: bufB[40] -> bufA[20]
    convs24(bufB, 40, bufA, 20, c2w, c2b, n2g, n2b, t, 1024);
    __syncthreads();
    // conv3: bufA[20] -> bufB[10]
    convs24(bufA, 20, bufB, 10, c3w, c3b, n3g, n3b, t, 1024);
    __syncthreads();

    // conv4: bufB[10][10][24] -> Xf[(b*25+p)][32] (+coords, pad)
    for (int p = t; p < 25; p += 1024) {
        int ow = p % 5, oh = p / 5;
        float acc[24];
        #pragma unroll
        for (int co = 0; co < 24; ++co) acc[co] = 0.f;
        int ih0 = 2 * oh - 1, iw0 = 2 * ow - 1;
        #pragma unroll 1
        for (int ky = 0; ky < 3; ++ky) {
            int ih = ih0 + ky; if (ih < 0) continue;
            #pragma unroll 1
            for (int kx = 0; kx < 3; ++kx) {
                int iw = iw0 + kx; if (iw < 0) continue;
                const unsigned short* pp = bufB + (ih * 10 + iw) * 24;
                u16x4 v[6];
                #pragma unroll
                for (int m = 0; m < 6; ++m) v[m] = *(const u16x4*)(pp + m * 4);
                float x[24];
                #pragma unroll
                for (int m = 0; m < 6; ++m)
                    #pragma unroll
                    for (int e = 0; e < 4; ++e) x[m * 4 + e] = bf2f(v[m][e]);
                int kb = ky * 3 + kx;
                #pragma unroll
                for (int ci = 0; ci < 24; ++ci) {
                    float xv = x[ci];
                    #pragma unroll
                    for (int co = 0; co < 24; ++co)
                        acc[co] += xv * c4w[co * 216 + ci * 9 + kb];
                }
            }
        }
        unsigned short* op = Xf + ((size_t)b * 25 + p) * 32;
        u16x8 o[4];
        #pragma unroll
        for (int co = 0; co < 24; ++co) {
            float scale = n4g[co] * 0.9999950000374997f;
            o[co >> 3][co & 7] = f2bf((acc[co] + c4b[co]) * scale + n4b[co]);
        }
        o[3][0] = f2bf((oh - 2) * 0.5f);
        o[3][1] = f2bf((ow - 2) * 0.5f);
        #pragma unroll
        for (int e = 2; e < 8; ++e) o[3][e] = 0;
        #pragma unroll
        for (int m = 0; m < 4; ++m) *(u16x8*)(op + m * 8) = o[m];
    }
}

// ---------- prep_misc: W1t + wt(g2,g3,g4,f1,f2) + wt3(f3) + zero(xg) + Cq ----------
__global__ void prep_misc_kernel(const float* __restrict__ g1w, const float* __restrict__ g1b,
                                 const float* __restrict__ g2w, const float* __restrict__ g3w,
                                 const float* __restrict__ g4w, const float* __restrict__ f1w,
                                 const float* __restrict__ f2w, const float* __restrict__ f3w,
                                 const float* __restrict__ q,
                                 unsigned short* __restrict__ W1t,
                                 unsigned short* __restrict__ wg2, unsigned short* __restrict__ wg3,
                                 unsigned short* __restrict__ wg4, unsigned short* __restrict__ wf1,
                                 unsigned short* __restrict__ wf2, unsigned short* __restrict__ wt3,
                                 float* __restrict__ xg, float* __restrict__ Cq)
{
    int blk = blockIdx.x, t = threadIdx.x;
    if (blk < 64) {                                     // W1t [512][32]
        int i = blk * 256 + t;
        int u = i >> 5, k = i & 31;
        float v = 0.f;
        if (k < 26) v = (u < 256) ? g1w[u * 63 + k] : g1w[(u - 256) * 63 + 26 + k];
        W1t[i] = f2bf(v);
    } else if (blk < 1344) {                            // wt layout [kk][u][32]
        int s = blk - 64;
        int which = s >> 8;
        int i = (s & 255) * 256 + t;
        int kin = i & 31, u = (i >> 5) & 255, kk = i >> 13;
        const float* w = (which == 0) ? g2w : (which == 1) ? g3w :
                         (which == 2) ? g4w : (which == 3) ? f1w : f2w;
        unsigned short* wt = (which == 0) ? wg2 : (which == 1) ? wg3 :
                             (which == 2) ? wg4 : (which == 3) ? wf1 : wf2;
        wt[i] = f2bf(w[u * 256 + kk * 32 + kin]);
    } else if (blk < 1360) {                            // wt3 [kk][16][32], u>=10 zero
        int i = (blk - 1344) * 256 + t;
        int kin = i & 31, u = (i >> 5) & 15, kk = i >> 9;
        wt3[i] = (u < 10) ? f2bf(f3w[u * 256 + kk * 32 + kin]) : 0;
    } else if (blk < 1872) {                            // zero xg
        xg[(size_t)(blk - 1360) * 256 + t] = 0.f;
    } else {                                            // Cq[b][u]
        int b = blk - 1872, u = t;
        float acc = g1b[u];
        #pragma unroll
        for (int k = 0; k < 11; ++k)
            acc += g1w[u * 63 + 52 + k] * q[b * 11 + k];
        Cq[(size_t)b * 256 + u] = acc;
    }
}

// ---------- prep GEMM: Xf[12800x32] x W1t -> A(+Cq folded), Bv bf16 ----------
__global__ __launch_bounds__(512) void prep_gemm_kernel(
    const unsigned short* __restrict__ Xf, const unsigned short* __restrict__ W1t,
    const float* __restrict__ Cq,
    unsigned short* __restrict__ A, unsigned short* __restrict__ Bv)
{
    int t = threadIdx.x, w8 = t >> 6, lane = t & 63;
    int rg = w8 & 3, cg = w8 >> 2;
    int lr = lane & 15, lh = lane >> 4;
    int row = blockIdx.x * 64 + rg * 16 + lr;
    bf16x8 af = *(const bf16x8*)(Xf + (size_t)row * 32 + lh * 8);
    f32x4 acc[16];
    #pragma unroll
    for (int ct = 0; ct < 16; ++ct) {
        int c0 = cg * 256 + ct * 16;
        bf16x8 bf = *(const bf16x8*)(W1t + (size_t)(c0 + lr) * 32 + lh * 8);
        acc[ct] = __builtin_amdgcn_mfma_f32_16x16x32_bf16(af, bf, (f32x4){0.f,0.f,0.f,0.f}, 0, 0, 0);
    }
    unsigned short* dst = (cg == 0) ? A : Bv;
    #pragma unroll
    for (int ct = 0; ct < 16; ++ct) {
        int col = ct * 16 + lr;
        #pragma unroll
        for (int reg = 0; reg < 4; ++reg) {
            int orow = blockIdx.x * 64 + rg * 16 + lh * 4 + reg;
            float v = acc[ct][reg];
            if (cg == 0) v += Cq[(orow / 25) * 256 + col];
            dst[(size_t)orow * 256 + col] = f2bf(v);
        }
    }
}

// ---------- gemm over 128 rows: wave = 128 rows x 64 cols ----------
template<bool SWAP>
__device__ __forceinline__ void gemm_k128(const unsigned short* __restrict__ W,
                                          const unsigned short* X,
                                          int lr, int lh, int wc, f32x4 acc[8][4])
{
    bf16x8 bcur[4], bnxt[4];
    #pragma unroll
    for (int cb = 0; cb < 4; ++cb)
        bcur[cb] = *(const bf16x8*)(W + (wc + cb * 16 + lr) * 32 + lh * 8);
    #pragma unroll
    for (int kk = 0; kk < 8; ++kk) {
        if (kk < 7) {
            #pragma unroll
            for (int cb = 0; cb < 4; ++cb)
                bnxt[cb] = *(const bf16x8*)(W + (size_t)(kk + 1) * 8192 + (wc + cb * 16 + lr) * 32 + lh * 8);
        }
        #pragma unroll
        for (int rb = 0; rb < 8; ++rb) {
            int row = rb * 16 + lr;
            int sg = (kk * 4 + lh) ^ (row & 15);
            bf16x8 af = *(const bf16x8*)(X + row * 256 + sg * 8);
            #pragma unroll
            for (int cb = 0; cb < 4; ++cb)
                acc[rb][cb] = SWAP
                    ? __builtin_amdgcn_mfma_f32_16x16x32_bf16(bcur[cb], af, acc[rb][cb], 0, 0, 0)
                    : __builtin_amdgcn_mfma_f32_16x16x32_bf16(af, bcur[cb], acc[rb][cb], 0, 0, 0);
        }
        #pragma unroll
        for (int cb = 0; cb < 4; ++cb) bcur[cb] = bnxt[cb];
    }
}

// ---------- gemm over 64 rows (fc) ----------
template<bool SWAP>
__device__ __forceinline__ void gemm_k64(const unsigned short* __restrict__ W,
                                         const unsigned short* X,
                                         int lr, int lh, int wc, f32x4 acc[4][4])
{
    bf16x8 bcur[4], bnxt[4];
    #pragma unroll
    for (int cb = 0; cb < 4; ++cb)
        bcur[cb] = *(const bf16x8*)(W + (wc + cb * 16 + lr) * 32 + lh * 8);
    #pragma unroll
    for (int kk = 0; kk < 8; ++kk) {
        if (kk < 7) {
            #pragma unroll
            for (int cb = 0; cb < 4; ++cb)
                bnxt[cb] = *(const bf16x8*)(W + (size_t)(kk + 1) * 8192 + (wc + cb * 16 + lr) * 32 + lh * 8);
        }
        #pragma unroll
        for (int rb = 0; rb < 4; ++rb) {
            int row = rb * 16 + lr;
            int sg = (kk * 4 + lh) ^ (row & 15);
            bf16x8 af = *(const bf16x8*)(X + row * 256 + sg * 8);
            #pragma unroll
            for (int cb = 0; cb < 4; ++cb)
                acc[rb][cb] = SWAP
                    ? __builtin_amdgcn_mfma_f32_16x16x32_bf16(bcur[cb], af, acc[rb][cb], 0, 0, 0)
                    : __builtin_amdgcn_mfma_f32_16x16x32_bf16(af, bcur[cb], acc[rb][cb], 0, 0, 0);
        }
        #pragma unroll
        for (int cb = 0; cb < 4; ++cb) bcur[cb] = bnxt[cb];
    }
}

// ---------- fused g2/g3/g4 + pair-sum; 128-row tile, 64KB LDS, 4 waves ----------
__global__ __launch_bounds__(256, 2) void gmlp_kernel(
    const unsigned short* __restrict__ A, const unsigned short* __restrict__ Bv,
    const unsigned short* __restrict__ w2, const float* __restrict__ b2,
    const unsigned short* __restrict__ w3, const float* __restrict__ b3,
    const unsigned short* __restrict__ w4, const float* __restrict__ b4,
    float* __restrict__ xg)
{
    __shared__ unsigned short X[128 * 256];   // 64 KB

    int blk  = blockIdx.x;
    int b    = blk / 5;
    int tile = blk % 5;
    int row0 = tile * 128;
    int t = threadIdx.x;

    {
        int r = t >> 1, half = t & 1;
        int prow = row0 + r;
        if (prow < 625) {
            int i = prow / 25, j = prow % 25;
            const unsigned short* Ap = A  + ((size_t)b * 25 + j) * 256;
            const unsigned short* Bp = Bv + ((size_t)b * 25 + i) * 256;
            #pragma unroll
            for (int k = 0; k < 16; ++k) {
                int g = half + 2 * k;
                int c0 = g * 8;
                u16x8 av = *(const u16x8*)(Ap + c0);
                u16x8 bv = *(const u16x8*)(Bp + c0);
                float v[8];
                #pragma unroll
                for (int e = 0; e < 8; ++e)
                    v[e] = fmaxf(bf2f(av[e]) + bf2f(bv[e]), 0.f);
                u32x4 o = { cvtpk(v[0], v[1]), cvtpk(v[2], v[3]),
                            cvtpk(v[4], v[5]), cvtpk(v[6], v[7]) };
                int sg = g ^ (r & 15);
                *(u32x4*)(X + r * 256 + sg * 8) = o;
            }
        } else {
            u32x4 z = {0, 0, 0, 0};
            #pragma unroll
            for (int k = 0; k < 16; ++k) {
                int g = half + 2 * k;
                int sg = g ^ (r & 15);
                *(u32x4*)(X + r * 256 + sg * 8) = z;
            }
        }
    }
    __syncthreads();

    int wid = t >> 6, lane = t & 63;
    int wc = wid * 64;
    int lr = lane & 15, lh = lane >> 4;

    const unsigned short* Wsw[2] = { w2, w3 };
    const float* Bsw[2] = { b2, b3 };
    #pragma unroll 1
    for (int L = 0; L < 2; ++L) {
        f32x4 acc[8][4];
        #pragma unroll
        for (int rb = 0; rb < 8; ++rb)
            #pragma unroll
            for (int cb = 0; cb < 4; ++cb) acc[rb][cb] = (f32x4){0.f,0.f,0.f,0.f};
        gemm_k128<true>(Wsw[L], X, lr, lh, wc, acc);

        f32x4 bsw[4];
        #pragma unroll
        for (int cb = 0; cb < 4; ++cb)
            bsw[cb] = *(const f32x4*)(Bsw[L] + wc + cb * 16 + lh * 4);

        __syncthreads();
        #pragma unroll
        for (int rb = 0; rb < 8; ++rb) {
            int prow = rb * 16 + lr;
            #pragma unroll
            for (int cb = 0; cb < 4; ++cb) {
                float v0 = fmaxf(acc[rb][cb][0] + bsw[cb][0], 0.f);
                float v1 = fmaxf(acc[rb][cb][1] + bsw[cb][1], 0.f);
                float v2 = fmaxf(acc[rb][cb][2] + bsw[cb][2], 0.f);
                float v3 = fmaxf(acc[rb][cb][3] + bsw[cb][3], 0.f);
                unsigned int w0 = cvtpk(v0, v1), w1 = cvtpk(v2, v3);
                int u0 = wc + cb * 16 + lh * 4;
                int sg = (u0 >> 3) ^ (prow & 15);
                unsigned int* dst = (unsigned int*)(X + prow * 256 + sg * 8 + (u0 & 7));
                dst[0] = w0; dst[1] = w1;
            }
        }
        __syncthreads();
    }

    {
        f32x4 acc[8][4];
        #pragma unroll
        for (int rb = 0; rb < 8; ++rb)
            #pragma unroll
            for (int cb = 0; cb < 4; ++cb) acc[rb][cb] = (f32x4){0.f,0.f,0.f,0.f};
        gemm_k128<false>(w4, X, lr, lh, wc, acc);

        float bias[4];
        #pragma unroll
        for (int cb = 0; cb < 4; ++cb) bias[cb] = b4[wc + cb * 16 + lr];

        float csum[4] = {0.f, 0.f, 0.f, 0.f};
        #pragma unroll
        for (int rb = 0; rb < 8; ++rb) {
            #pragma unroll
            for (int reg = 0; reg < 4; ++reg) {
                int rowloc = rb * 16 + lh * 4 + reg;
                bool valid = (row0 + rowloc) < 625;
                #pragma unroll
                for (int cb = 0; cb < 4; ++cb) {
                    float v = fmaxf(acc[rb][cb][reg] + bias[cb], 0.f);
                    if (valid) csum[cb] += v;
                }
            }
        }
        #pragma unroll
        for (int cb = 0; cb < 4; ++cb) {
            csum[cb] += __shfl_xor(csum[cb], 16);
            csum[cb] += __shfl_xor(csum[cb], 32);
        }
        if (lh == 0) {
            #pragma unroll
            for (int cb = 0; cb < 4; ++cb)
                atomicAdd(&xg[(size_t)b * 256 + wc + cb * 16 + lr], csum[cb]);
        }
    }
}

// ---------- fc via MFMA: 8 blocks x 64 batch rows; f1,f2 in-place in LDS; f3 on wave0 ----------
__global__ __launch_bounds__(256) void fc_mfma_kernel(
    const float* __restrict__ xg,
    const unsigned short* __restrict__ wf1, const float* __restrict__ f1b,
    const unsigned short* __restrict__ wf2, const float* __restrict__ f2b,
    const unsigned short* __restrict__ wt3, const float* __restrict__ f3b,
    float* __restrict__ out)
{
    __shared__ unsigned short X[64 * 256];   // 32 KB
    int r0 = blockIdx.x * 64;
    int t = threadIdx.x;

    // stage xg rows (fp32 -> bf16, swizzled)
    {
        int r = t >> 2, quad = t & 3;
        const float* Sp = xg + (size_t)(r0 + r) * 256;
        #pragma unroll
        for (int k = 0; k < 8; ++k) {
            int g = quad + 4 * k;
            int c0 = g * 8;
            f32x4 a0 = *(const f32x4*)(Sp + c0);
            f32x4 a1 = *(const f32x4*)(Sp + c0 + 4);
            u32x4 o = { cvtpk(a0[0], a0[1]), cvtpk(a0[2], a0[3]),
                        cvtpk(a1[0], a1[1]), cvtpk(a1[2], a1[3]) };
            int sg = g ^ (r & 15);
            *(u32x4*)(X + r * 256 + sg * 8) = o;
        }
    }
    __syncthreads();

    int wid = t >> 6, lane = t & 63;
    int wc = wid * 64;
    int lr = lane & 15, lh = lane >> 4;

    const unsigned short* Ws[2] = { wf1, wf2 };
    const float* Bs[2] = { f1b, f2b };
    #pragma unroll 1
    for (int L = 0; L < 2; ++L) {
        f32x4 acc[4][4];
        #pragma unroll
        for (int rb = 0; rb < 4; ++rb)
            #pragma unroll
            for (int cb = 0; cb < 4; ++cb) acc[rb][cb] = (f32x4){0.f,0.f,0.f,0.f};
        gemm_k64<true>(Ws[L], X, lr, lh, wc, acc);

        f32x4 bsw[4];
        #pragma unroll
        for (int cb = 0; cb < 4; ++cb)
            bsw[cb] = *(const f32x4*)(Bs[L] + wc + cb * 16 + lh * 4);

        __syncthreads();
        #pragma unroll
        for (int rb = 0; rb < 4; ++rb) {
            int prow = rb * 16 + lr;
            #pragma unroll
            for (int cb = 0; cb < 4; ++cb) {
                float v0 = fmaxf(acc[rb][cb][0] + bsw[cb][0], 0.f);
                float v1 = fmaxf(acc[rb][cb][1] + bsw[cb][1], 0.f);
                float v2 = fmaxf(acc[rb][cb][2] + bsw[cb][2], 0.f);
                float v3 = fmaxf(acc[rb][cb][3] + bsw[cb][3], 0.f);
                unsigned int w0 = cvtpk(v0, v1), w1 = cvtpk(v2, v3);
                int u0 = wc + cb * 16 + lh * 4;
                int sg = (u0 >> 3) ^ (prow & 15);
                unsigned int* dst = (unsigned int*)(X + prow * 256 + sg * 8 + (u0 & 7));
                dst[0] = w0; dst[1] = w1;
            }
        }
        __syncthreads();
    }

    // f3: wave 0, swapped, 16 padded output rows (u), 64 cols (batch rows)
    if (wid == 0) {
        f32x4 acc3[4];
        #pragma unroll
        for (int rb = 0; rb < 4; ++rb) acc3[rb] = (f32x4){0.f,0.f,0.f,0.f};
        #pragma unroll
        for (int kk = 0; kk < 8; ++kk) {
            bf16x8 wfrag = *(const bf16x8*)(wt3 + (size_t)kk * 512 + lr * 32 + lh * 8);
            #pragma unroll
            for (int rb = 0; rb < 4; ++rb) {
                int row = rb * 16 + lr;
                int sg = (kk * 4 + lh) ^ (row & 15);
                bf16x8 af = *(const bf16x8*)(X + row * 256 + sg * 8);
                acc3[rb] = __builtin_amdgcn_mfma_f32_16x16x32_bf16(wfrag, af, acc3[rb], 0, 0, 0);
            }
        }
        #pragma unroll
        for (int rb = 0; rb < 4; ++rb) {
            int prow = rb * 16 + lr;
            #pragma unroll
            for (int reg = 0; reg < 4; ++reg) {
                int u = lh * 4 + reg;
                if (u < 10) out[(size_t)(r0 + prow) * 10 + u] = acc3[rb][reg] + f3b[u];
            }
        }
    }
}

// ---------- launch ----------
extern "C" void kernel_launch(void* const* d_in, const int* in_sizes, int n_in,
                              void* d_out, int out_size, void* d_ws, size_t ws_size,
                              hipStream_t stream)
{
    const float* im  = (const float*)d_in[0];
    const float* q   = (const float*)d_in[1];
    const float* c1w = (const float*)d_in[2];
    const float* c1b = (const float*)d_in[3];
    const float* n1g = (const float*)d_in[4];
    const float* n1b = (const float*)d_in[5];
    const float* c2w = (const float*)d_in[6];
    const float* c2b = (const float*)d_in[7];
    const float* n2g = (const float*)d_in[8];
    const float* n2b = (const float*)d_in[9];
    const float* c3w = (const float*)d_in[10];
    const float* c3b = (const float*)d_in[11];
    const float* n3g = (const float*)d_in[12];
    const float* n3b = (const float*)d_in[13];
    const float* c4w = (const float*)d_in[14];
    const float* c4b = (const float*)d_in[15];
    const float* n4g = (const float*)d_in[16];
    const float* n4b = (const float*)d_in[17];
    const float* g1w = (const float*)d_in[18];
    const float* g1b = (const float*)d_in[19];
    const float* g2w = (const float*)d_in[20];
    const float* g2b = (const float*)d_in[21];
    const float* g3w = (const float*)d_in[22];
    const float* g3b = (const float*)d_in[23];
    const float* g4w = (const float*)d_in[24];
    const float* g4b = (const float*)d_in[25];
    const float* f1w = (const float*)d_in[26];
    const float* f1b = (const float*)d_in[27];
    const float* f2w = (const float*)d_in[28];
    const float* f2b = (const float*)d_in[29];
    const float* f3w = (const float*)d_in[30];
    const float* f3b = (const float*)d_in[31];

    char* ws = (char*)d_ws;
    size_t off = 0;
    auto alloc = [&](size_t bytes) -> void* {
        void* p = ws + off;
        off += (bytes + 255) & ~(size_t)255;
        return p;
    };
    unsigned short* A   = (unsigned short*)alloc(3276800ull * 2);
    unsigned short* Bv  = (unsigned short*)alloc(3276800ull * 2);
    unsigned short* Xf  = (unsigned short*)alloc(409600ull * 2);
    unsigned short* W1t = (unsigned short*)alloc(16384ull * 2);
    unsigned short* wg2 = (unsigned short*)alloc(65536ull * 2);
    unsigned short* wg3 = (unsigned short*)alloc(65536ull * 2);
    unsigned short* wg4 = (unsigned short*)alloc(65536ull * 2);
    unsigned short* wf1 = (unsigned short*)alloc(65536ull * 2);
    unsigned short* wf2 = (unsigned short*)alloc(65536ull * 2);
    unsigned short* wt3 = (unsigned short*)alloc(4096ull * 2);
    float* Cq  = (float*)alloc(131072ull * 4);
    float* xg  = (float*)alloc(131072ull * 4);

    conv_fused_kernel<<<512, 1024, 115200, stream>>>(im,
        c1w, c1b, n1g, n1b, c2w, c2b, n2g, n2b,
        c3w, c3b, n3g, n3b, c4w, c4b, n4g, n4b, Xf);

    prep_misc_kernel<<<2384, 256, 0, stream>>>(g1w, g1b, g2w, g3w, g4w, f1w, f2w, f3w, q,
                                               W1t, wg2, wg3, wg4, wf1, wf2, wt3, xg, Cq);

    prep_gemm_kernel<<<200, 512, 0, stream>>>(Xf, W1t, Cq, A, Bv);

    gmlp_kernel<<<512 * 5, 256, 0, stream>>>(A, Bv, wg2, g2b, wg3, g3b, wg4, g4b, xg);

    fc_mfma_kernel<<<8, 256, 0, stream>>>(xg, wf1, f1b, wf2, f2b, wt3, f3b, (float*)d_out);
}

// Round 10
// 367.614 us; speedup vs baseline: 1.3357x; 1.3357x over previous
//
#include <hip/hip_runtime.h>
#include <stdint.h>

typedef short     bf16x8  __attribute__((ext_vector_type(8)));
typedef float     f32x4   __attribute__((ext_vector_type(4)));
typedef unsigned short u16x8 __attribute__((ext_vector_type(8)));
typedef unsigned short u16x4 __attribute__((ext_vector_type(4)));
typedef unsigned int   u32x4 __attribute__((ext_vector_type(4)));

__device__ __forceinline__ float bf2f(unsigned short u) {
    union { unsigned int i; float f; } v; v.i = ((unsigned int)u) << 16; return v.f;
}
__device__ __forceinline__ unsigned short f2bf(float f) {
    union { float f; unsigned int i; } v; v.f = f;
    unsigned int x = v.i;
    return (unsigned short)((x + 0x7fffu + ((x >> 16) & 1u)) >> 16);
}
__device__ __forceinline__ unsigned int cvtpk(float lo, float hi) {
    unsigned int r;
    asm("v_cvt_pk_bf16_f32 %0, %1, %2" : "=v"(r) : "v"(lo), "v"(hi));
    return r;
}

// ---------- 24->24 stride-2 conv step, LDS -> LDS, NHWC ----------
// Weights in wc layout [kb][ci][co] (fp32): inner co-loop reads consecutive floats.
// NCO = output channels per thread (24/NCO threads cooperate per pixel).
template<int NCO>
__device__ __forceinline__ void convs24_split(const unsigned short* __restrict__ in, int H,
                                              unsigned short* __restrict__ out, int OH,
                                              const float* __restrict__ wc, const float* __restrict__ bias,
                                              const float* __restrict__ bng, const float* __restrict__ bnb,
                                              int t, int nthr)
{
    const int per = 24 / NCO;
    int total = OH * OH * per;
    for (int s = t; s < total; s += nthr) {
        int p = s / per, sc = s % per, co0 = sc * NCO;
        int ow = p % OH, oh = p / OH;
        float acc[NCO];
        #pragma unroll
        for (int c = 0; c < NCO; ++c) acc[c] = 0.f;
        int ih0 = 2 * oh - 1, iw0 = 2 * ow - 1;
        #pragma unroll 1
        for (int ky = 0; ky < 3; ++ky) {
            int ih = ih0 + ky; if (ih < 0) continue;
            #pragma unroll 1
            for (int kx = 0; kx < 3; ++kx) {
                int iw = iw0 + kx; if (iw < 0) continue;
                const unsigned short* pp = in + (ih * H + iw) * 24;
                u16x4 v[6];
                #pragma unroll
                for (int m = 0; m < 6; ++m) v[m] = *(const u16x4*)(pp + m * 4);
                float x[24];
                #pragma unroll
                for (int m = 0; m < 6; ++m)
                    #pragma unroll
                    for (int e = 0; e < 4; ++e) x[m * 4 + e] = bf2f(v[m][e]);
                int kb = ky * 3 + kx;
                const float* wk = wc + kb * 576 + co0;
                #pragma unroll
                for (int ci = 0; ci < 24; ++ci) {
                    float xv = x[ci];
                    #pragma unroll
                    for (int c = 0; c < NCO; ++c)
                        acc[c] += xv * wk[ci * 24 + c];
                }
            }
        }
        unsigned short* op = out + p * 24 + co0;
        #pragma unroll
        for (int c4i = 0; c4i < NCO / 4; ++c4i) {
            u16x4 o;
            #pragma unroll
            for (int e = 0; e < 4; ++e) {
                int co = co0 + c4i * 4 + e;
                float scale = bng[co] * 0.9999950000374997f;
                o[e] = f2bf((acc[c4i * 4 + e] + bias[co]) * scale + bnb[co]);
            }
            *(u16x4*)(op + c4i * 4) = o;
        }
    }
}

// ---------- fully fused conv1..conv4: one block per image; writes only Xf ----------
__global__ __launch_bounds__(1024) void conv_fused_kernel(
    const float* __restrict__ im,
    const float* __restrict__ wc1, const float* __restrict__ c1b,
    const float* __restrict__ n1g, const float* __restrict__ n1b,
    const float* __restrict__ wc2, const float* __restrict__ c2b,
    const float* __restrict__ n2g, const float* __restrict__ n2b,
    const float* __restrict__ wc3, const float* __restrict__ c3b,
    const float* __restrict__ n3g, const float* __restrict__ n3b,
    const float* __restrict__ wc4, const float* __restrict__ c4b,
    const float* __restrict__ n4g, const float* __restrict__ n4b,
    unsigned short* __restrict__ Xf)
{
    extern __shared__ unsigned short smem[];
    unsigned short* bufA = smem;            // 19200: im bf16; later c2 (9600)
    unsigned short* bufB = smem + 19200;    // 38400: c1; later c3 (2400)
    int b = blockIdx.x, t = threadIdx.x;

    // stage image (fp32 -> bf16, coalesced)
    const float* ip = im + (size_t)b * 19200;
    for (int i = t; i < 19200; i += 1024) bufA[i] = f2bf(ip[i]);
    __syncthreads();

    // conv1: bufA [3][80][80] -> bufB [40][40][24]; wc1 layout [k][co], k = ci*9+ky*3+kx
    for (int p = t; p < 1600; p += 1024) {
        int ow = p % 40, oh = p / 40;
        float acc[24];
        #pragma unroll
        for (int co = 0; co < 24; ++co) acc[co] = 0.f;
        int ih0 = 2 * oh - 1, iw0 = 2 * ow - 1;
        #pragma unroll 1
        for (int ci = 0; ci < 3; ++ci) {
            #pragma unroll 1
            for (int ky = 0; ky < 3; ++ky) {
                int ih = ih0 + ky; if (ih < 0) continue;
                #pragma unroll 1
                for (int kx = 0; kx < 3; ++kx) {
                    int iw = iw0 + kx; if (iw < 0) continue;
                    float x = bf2f(bufA[ci * 6400 + ih * 80 + iw]);
                    const float* wk = wc1 + (ci * 9 + ky * 3 + kx) * 24;
                    #pragma unroll
                    for (int co = 0; co < 24; ++co) acc[co] += x * wk[co];
                }
            }
        }
        unsigned short* op = bufB + p * 24;
        u16x4 o[6];
        #pragma unroll
        for (int co = 0; co < 24; ++co) {
            float scale = n1g[co] * 0.9999950000374997f;
            o[co >> 2][co & 3] = f2bf((acc[co] + c1b[co]) * scale + n1b[co]);
        }
        #pragma unroll
        for (int m = 0; m < 6; ++m) *(u16x4*)(op + m * 4) = o[m];
    }
    __syncthreads();

    // conv2: bufB[40] -> bufA[20], 2 threads/pixel
    convs24_split<12>(bufB, 40, bufA, 20, wc2, c2b, n2g, n2b, t, 1024);
    __syncthreads();
    // conv3: bufA[20] -> bufB[10], 3 threads/pixel
    convs24_split<8>(bufA, 20, bufB, 10, wc3, c3b, n3g, n3b, t, 1024);
    __syncthreads();

    // conv4: bufB[10][10][24] -> Xf[(b*25+p)][32], 2 threads/pixel
    for (int s = t; s < 50; s += 1024) {
        int p = s >> 1, sc = s & 1, co0 = sc * 12;
        int ow = p % 5, oh = p / 5;
        float acc[12];
        #pragma unroll
        for (int c = 0; c < 12; ++c) acc[c] = 0.f;
        int ih0 = 2 * oh - 1, iw0 = 2 * ow - 1;
        #pragma unroll 1
        for (int ky = 0; ky < 3; ++ky) {
            int ih = ih0 + ky; if (ih < 0) continue;
            #pragma unroll 1
            for (int kx = 0; kx < 3; ++kx) {
                int iw = iw0 + kx; if (iw < 0) continue;
                const unsigned short* pp = bufB + (ih * 10 + iw) * 24;
                u16x4 v[6];
                #pragma unroll
                for (int m = 0; m < 6; ++m) v[m] = *(const u16x4*)(pp + m * 4);
                float x[24];
                #pragma unroll
                for (int m = 0; m < 6; ++m)
                    #pragma unroll
                    for (int e = 0; e < 4; ++e) x[m * 4 + e] = bf2f(v[m][e]);
                int kb = ky * 3 + kx;
                const float* wk = wc4 + kb * 576 + co0;
                #pragma unroll
                for (int ci = 0; ci < 24; ++ci) {
                    float xv = x[ci];
                    #pragma unroll
                    for (int c = 0; c < 12; ++c)
                        acc[c] += xv * wk[ci * 24 + c];
                }
            }
        }
        unsigned short* op = Xf + ((size_t)b * 25 + p) * 32 + co0;
        #pragma unroll
        for (int c4i = 0; c4i < 3; ++c4i) {
            u16x4 o;
            #pragma unroll
            for (int e = 0; e < 4; ++e) {
                int co = co0 + c4i * 4 + e;
                float scale = n4g[co] * 0.9999950000374997f;
                o[e] = f2bf((acc[c4i * 4 + e] + c4b[co]) * scale + n4b[co]);
            }
            *(u16x4*)(op + c4i * 4) = o;
        }
        if (sc == 1) {   // coords + zero pad (cols 24..31)
            u16x8 o;
            o[0] = f2bf((oh - 2) * 0.5f);
            o[1] = f2bf((ow - 2) * 0.5f);
            #pragma unroll
            for (int e = 2; e < 8; ++e) o[e] = 0;
            *(u16x8*)(Xf + ((size_t)b * 25 + p) * 32 + 24) = o;
        }
    }
}

// ---------- prep_misc: W1t + wt(g2,g3,g4,f1,f2) + wt3(f3) + zero(xg) + Cq + conv wc ----------
__global__ void prep_misc_kernel(const float* __restrict__ g1w, const float* __restrict__ g1b,
                                 const float* __restrict__ g2w, const float* __restrict__ g3w,
                                 const float* __restrict__ g4w, const float* __restrict__ f1w,
                                 const float* __restrict__ f2w, const float* __restrict__ f3w,
                                 const float* __restrict__ q,
                                 const float* __restrict__ c1w, const float* __restrict__ c2w,
                                 const float* __restrict__ c3w, const float* __restrict__ c4w,
                                 unsigned short* __restrict__ W1t,
                                 unsigned short* __restrict__ wg2, unsigned short* __restrict__ wg3,
                                 unsigned short* __restrict__ wg4, unsigned short* __restrict__ wf1,
                                 unsigned short* __restrict__ wf2, unsigned short* __restrict__ wt3,
                                 float* __restrict__ xg, float* __restrict__ Cq,
                                 float* __restrict__ wc1, float* __restrict__ wc2,
                                 float* __restrict__ wc3, float* __restrict__ wc4)
{
    int blk = blockIdx.x, t = threadIdx.x;
    if (blk < 64) {                                     // W1t [512][32]
        int i = blk * 256 + t;
        int u = i >> 5, k = i & 31;
        float v = 0.f;
        if (k < 26) v = (u < 256) ? g1w[u * 63 + k] : g1w[(u - 256) * 63 + 26 + k];
        W1t[i] = f2bf(v);
    } else if (blk < 1344) {                            // wt layout [kk][u][32]
        int s = blk - 64;
        int which = s >> 8;
        int i = (s & 255) * 256 + t;
        int kin = i & 31, u = (i >> 5) & 255, kk = i >> 13;
        const float* w = (which == 0) ? g2w : (which == 1) ? g3w :
                         (which == 2) ? g4w : (which == 3) ? f1w : f2w;
        unsigned short* wt = (which == 0) ? wg2 : (which == 1) ? wg3 :
                             (which == 2) ? wg4 : (which == 3) ? wf1 : wf2;
        wt[i] = f2bf(w[u * 256 + kk * 32 + kin]);
    } else if (blk < 1360) {                            // wt3 [kk][16][32], u>=10 zero
        int i = (blk - 1344) * 256 + t;
        int kin = i & 31, u = (i >> 5) & 15, kk = i >> 9;
        wt3[i] = (u < 10) ? f2bf(f3w[u * 256 + kk * 32 + kin]) : 0;
    } else if (blk < 1872) {                            // zero xg
        xg[(size_t)(blk - 1360) * 256 + t] = 0.f;
    } else if (blk < 2384) {                            // Cq[b][u]
        int b = blk - 1872, u = t;
        float acc = g1b[u];
        #pragma unroll
        for (int k = 0; k < 11; ++k)
            acc += g1w[u * 63 + 52 + k] * q[b * 11 + k];
        Cq[(size_t)b * 256 + u] = acc;
    } else {                                            // conv weight transposes
        int i = (blk - 2384) * 256 + t;
        if (i < 648) {                                  // wc1[k][co] = c1w[co][k]
            int k = i / 24, co = i % 24;
            wc1[i] = c1w[co * 27 + k];
        } else if (i < 16200) {                         // wcN[kb][ci][co] = cNw[co][ci][kb]
            int j = i - 648;
            int which = j / 5184; j %= 5184;
            int kb = j / 576, r = j % 576, ci = r / 24, co = r % 24;
            const float* src = (which == 0) ? c2w : (which == 1) ? c3w : c4w;
            float* dst = (which == 0) ? wc2 : (which == 1) ? wc3 : wc4;
            dst[j] = src[co * 216 + ci * 9 + kb];
        }
    }
}

// ---------- prep GEMM: Xf[12800x32] x W1t -> A(+Cq folded), Bv bf16 ----------
__global__ __launch_bounds__(512) void prep_gemm_kernel(
    const unsigned short* __restrict__ Xf, const unsigned short* __restrict__ W1t,
    const float* __restrict__ Cq,
    unsigned short* __restrict__ A, unsigned short* __restrict__ Bv)
{
    int t = threadIdx.x, w8 = t >> 6, lane = t & 63;
    int rg = w8 & 3, cg = w8 >> 2;
    int lr = lane & 15, lh = lane >> 4;
    int row = blockIdx.x * 64 + rg * 16 + lr;
    bf16x8 af = *(const bf16x8*)(Xf + (size_t)row * 32 + lh * 8);
    f32x4 acc[16];
    #pragma unroll
    for (int ct = 0; ct < 16; ++ct) {
        int c0 = cg * 256 + ct * 16;
        bf16x8 bf = *(const bf16x8*)(W1t + (size_t)(c0 + lr) * 32 + lh * 8);
        acc[ct] = __builtin_amdgcn_mfma_f32_16x16x32_bf16(af, bf, (f32x4){0.f,0.f,0.f,0.f}, 0, 0, 0);
    }
    unsigned short* dst = (cg == 0) ? A : Bv;
    #pragma unroll
    for (int ct = 0; ct < 16; ++ct) {
        int col = ct * 16 + lr;
        #pragma unroll
        for (int reg = 0; reg < 4; ++reg) {
            int orow = blockIdx.x * 64 + rg * 16 + lh * 4 + reg;
            float v = acc[ct][reg];
            if (cg == 0) v += Cq[(orow / 25) * 256 + col];
            dst[(size_t)orow * 256 + col] = f2bf(v);
        }
    }
}

// ---------- gemm over 128 rows: wave = 128 rows x 64 cols ----------
template<bool SWAP>
__device__ __forceinline__ void gemm_k128(const unsigned short* __restrict__ W,
                                          const unsigned short* X,
                                          int lr, int lh, int wc, f32x4 acc[8][4])
{
    bf16x8 bcur[4], bnxt[4];
    #pragma unroll
    for (int cb = 0; cb < 4; ++cb)
        bcur[cb] = *(const bf16x8*)(W + (wc + cb * 16 + lr) * 32 + lh * 8);
    #pragma unroll
    for (int kk = 0; kk < 8; ++kk) {
        if (kk < 7) {
            #pragma unroll
            for (int cb = 0; cb < 4; ++cb)
                bnxt[cb] = *(const bf16x8*)(W + (size_t)(kk + 1) * 8192 + (wc + cb * 16 + lr) * 32 + lh * 8);
        }
        #pragma unroll
        for (int rb = 0; rb < 8; ++rb) {
            int row = rb * 16 + lr;
            int sg = (kk * 4 + lh) ^ (row & 15);
            bf16x8 af = *(const bf16x8*)(X + row * 256 + sg * 8);
            #pragma unroll
            for (int cb = 0; cb < 4; ++cb)
                acc[rb][cb] = SWAP
                    ? __builtin_amdgcn_mfma_f32_16x16x32_bf16(bcur[cb], af, acc[rb][cb], 0, 0, 0)
                    : __builtin_amdgcn_mfma_f32_16x16x32_bf16(af, bcur[cb], acc[rb][cb], 0, 0, 0);
        }
        #pragma unroll
        for (int cb = 0; cb < 4; ++cb) bcur[cb] = bnxt[cb];
    }
}

// ---------- gemm over 64 rows (fc) ----------
template<bool SWAP>
__device__ __forceinline__ void gemm_k64(const unsigned short* __restrict__ W,
                                         const unsigned short* X,
                                         int lr, int lh, int wc, f32x4 acc[4][4])
{
    bf16x8 bcur[4], bnxt[4];
    #pragma unroll
    for (int cb = 0; cb < 4; ++cb)
        bcur[cb] = *(const bf16x8*)(W + (wc + cb * 16 + lr) * 32 + lh * 8);
    #pragma unroll
    for (int kk = 0; kk < 8; ++kk) {
        if (kk < 7) {
            #pragma unroll
            for (int cb = 0; cb < 4; ++cb)
                bnxt[cb] = *(const bf16x8*)(W + (size_t)(kk + 1) * 8192 + (wc + cb * 16 + lr) * 32 + lh * 8);
        }
        #pragma unroll
        for (int rb = 0; rb < 4; ++rb) {
            int row = rb * 16 + lr;
            int sg = (kk * 4 + lh) ^ (row & 15);
            bf16x8 af = *(const bf16x8*)(X + row * 256 + sg * 8);
            #pragma unroll
            for (int cb = 0; cb < 4; ++cb)
                acc[rb][cb] = SWAP
                    ? __builtin_amdgcn_mfma_f32_16x16x32_bf16(bcur[cb], af, acc[rb][cb], 0, 0, 0)
                    : __builtin_amdgcn_mfma_f32_16x16x32_bf16(af, bcur[cb], acc[rb][cb], 0, 0, 0);
        }
        #pragma unroll
        for (int cb = 0; cb < 4; ++cb) bcur[cb] = bnxt[cb];
    }
}

// ---------- fused g2/g3/g4 + pair-sum; 128-row tile, 64KB LDS, 4 waves ----------
__global__ __launch_bounds__(256, 2) void gmlp_kernel(
    const unsigned short* __restrict__ A, const unsigned short* __restrict__ Bv,
    const unsigned short* __restrict__ w2, const float* __restrict__ b2,
    const unsigned short* __restrict__ w3, const float* __restrict__ b3,
    const unsigned short* __restrict__ w4, const float* __restrict__ b4,
    float* __restrict__ xg)
{
    __shared__ unsigned short X[128 * 256];   // 64 KB

    int blk  = blockIdx.x;
    int b    = blk / 5;
    int tile = blk % 5;
    int row0 = tile * 128;
    int t = threadIdx.x;

    {
        int r = t >> 1, half = t & 1;
        int prow = row0 + r;
        if (prow < 625) {
            int i = prow / 25, j = prow % 25;
            const unsigned short* Ap = A  + ((size_t)b * 25 + j) * 256;
            const unsigned short* Bp = Bv + ((size_t)b * 25 + i) * 256;
            #pragma unroll
            for (int k = 0; k < 16; ++k) {
                int g = half + 2 * k;
                int c0 = g * 8;
                u16x8 av = *(const u16x8*)(Ap + c0);
                u16x8 bv = *(const u16x8*)(Bp + c0);
                float v[8];
                #pragma unroll
                for (int e = 0; e < 8; ++e)
                    v[e] = fmaxf(bf2f(av[e]) + bf2f(bv[e]), 0.f);
                u32x4 o = { cvtpk(v[0], v[1]), cvtpk(v[2], v[3]),
                            cvtpk(v[4], v[5]), cvtpk(v[6], v[7]) };
                int sg = g ^ (r & 15);
                *(u32x4*)(X + r * 256 + sg * 8) = o;
            }
        } else {
            u32x4 z = {0, 0, 0, 0};
            #pragma unroll
            for (int k = 0; k < 16; ++k) {
                int g = half + 2 * k;
                int sg = g ^ (r & 15);
                *(u32x4*)(X + r * 256 + sg * 8) = z;
            }
        }
    }
    __syncthreads();

    int wid = t >> 6, lane = t & 63;
    int wc = wid * 64;
    int lr = lane & 15, lh = lane >> 4;

    const unsigned short* Wsw[2] = { w2, w3 };
    const float* Bsw[2] = { b2, b3 };
    #pragma unroll 1
    for (int L = 0; L < 2; ++L) {
        f32x4 acc[8][4];
        #pragma unroll
        for (int rb = 0; rb < 8; ++rb)
            #pragma unroll
            for (int cb = 0; cb < 4; ++cb) acc[rb][cb] = (f32x4){0.f,0.f,0.f,0.f};
        gemm_k128<true>(Wsw[L], X, lr, lh, wc, acc);

        f32x4 bsw[4];
        #pragma unroll
        for (int cb = 0; cb < 4; ++cb)
            bsw[cb] = *(const f32x4*)(Bsw[L] + wc + cb * 16 + lh * 4);

        __syncthreads();
        #pragma unroll
        for (int rb = 0; rb < 8; ++rb) {
            int prow = rb * 16 + lr;
            #pragma unroll
            for (int cb = 0; cb < 4; ++cb) {
                float v0 = fmaxf(acc[rb][cb][0] + bsw[cb][0], 0.f);
                float v1 = fmaxf(acc[rb][cb][1] + bsw[cb][1], 0.f);
                float v2 = fmaxf(acc[rb][cb][2] + bsw[cb][2], 0.f);
                float v3 = fmaxf(acc[rb][cb][3] + bsw[cb][3], 0.f);
                unsigned int w0 = cvtpk(v0, v1), w1 = cvtpk(v2, v3);
                int u0 = wc + cb * 16 + lh * 4;
                int sg = (u0 >> 3) ^ (prow & 15);
                unsigned int* dst = (unsigned int*)(X + prow * 256 + sg * 8 + (u0 & 7));
                dst[0] = w0; dst[1] = w1;
            }
        }
        __syncthreads();
    }

    {
        f32x4 acc[8][4];
        #pragma unroll
        for (int rb = 0; rb < 8; ++rb)
            #pragma unroll
            for (int cb = 0; cb < 4; ++cb) acc[rb][cb] = (f32x4){0.f,0.f,0.f,0.f};
        gemm_k128<false>(w4, X, lr, lh, wc, acc);

        float bias[4];
        #pragma unroll
        for (int cb = 0; cb < 4; ++cb) bias[cb] = b4[wc + cb * 16 + lr];

        float csum[4] = {0.f, 0.f, 0.f, 0.f};
        #pragma unroll
        for (int rb = 0; rb < 8; ++rb) {
            #pragma unroll
            for (int reg = 0; reg < 4; ++reg) {
                int rowloc = rb * 16 + lh * 4 + reg;
                bool valid = (row0 + rowloc) < 625;
                #pragma unroll
                for (int cb = 0; cb < 4; ++cb) {
                    float v = fmaxf(acc[rb][cb][reg] + bias[cb], 0.f);
                    if (valid) csum[cb] += v;
                }
            }
        }
        #pragma unroll
        for (int cb = 0; cb < 4; ++cb) {
            csum[cb] += __shfl_xor(csum[cb], 16);
            csum[cb] += __shfl_xor(csum[cb], 32);
        }
        if (lh == 0) {
            #pragma unroll
            for (int cb = 0; cb < 4; ++cb)
                atomicAdd(&xg[(size_t)b * 256 + wc + cb * 16 + lr], csum[cb]);
        }
    }
}

// ---------- fc via MFMA: 8 blocks x 64 batch rows; f1,f2 in-place in LDS; f3 on wave0 ----------
__global__ __launch_bounds__(256) void fc_mfma_kernel(
    const float* __restrict__ xg,
    const unsigned short* __restrict__ wf1, const float* __restrict__ f1b,
    const unsigned short* __restrict__ wf2, const float* __restrict__ f2b,
    const unsigned short* __restrict__ wt3, const float* __restrict__ f3b,
    float* __restrict__ out)
{
    __shared__ unsigned short X[64 * 256];   // 32 KB
    int r0 = blockIdx.x * 64;
    int t = threadIdx.x;

    {
        int r = t >> 2, quad = t & 3;
        const float* Sp = xg + (size_t)(r0 + r) * 256;
        #pragma unroll
        for (int k = 0; k < 8; ++k) {
            int g = quad + 4 * k;
            int c0 = g * 8;
            f32x4 a0 = *(const f32x4*)(Sp + c0);
            f32x4 a1 = *(const f32x4*)(Sp + c0 + 4);
            u32x4 o = { cvtpk(a0[0], a0[1]), cvtpk(a0[2], a0[3]),
                        cvtpk(a1[0], a1[1]), cvtpk(a1[2], a1[3]) };
            int sg = g ^ (r & 15);
            *(u32x4*)(X + r * 256 + sg * 8) = o;
        }
    }
    __syncthreads();

    int wid = t >> 6, lane = t & 63;
    int wc = wid * 64;
    int lr = lane & 15, lh = lane >> 4;

    const unsigned short* Ws[2] = { wf1, wf2 };
    const float* Bs[2] = { f1b, f2b };
    #pragma unroll 1
    for (int L = 0; L < 2; ++L) {
        f32x4 acc[4][4];
        #pragma unroll
        for (int rb = 0; rb < 4; ++rb)
            #pragma unroll
            for (int cb = 0; cb < 4; ++cb) acc[rb][cb] = (f32x4){0.f,0.f,0.f,0.f};
        gemm_k64<true>(Ws[L], X, lr, lh, wc, acc);

        f32x4 bsw[4];
        #pragma unroll
        for (int cb = 0; cb < 4; ++cb)
            bsw[cb] = *(const f32x4*)(Bs[L] + wc + cb * 16 + lh * 4);

        __syncthreads();
        #pragma unroll
        for (int rb = 0; rb < 4; ++rb) {
            int prow = rb * 16 + lr;
            #pragma unroll
            for (int cb = 0; cb < 4; ++cb) {
                float v0 = fmaxf(acc[rb][cb][0] + bsw[cb][0], 0.f);
                float v1 = fmaxf(acc[rb][cb][1] + bsw[cb][1], 0.f);
                float v2 = fmaxf(acc[rb][cb][2] + bsw[cb][2], 0.f);
                float v3 = fmaxf(acc[rb][cb][3] + bsw[cb][3], 0.f);
                unsigned int w0 = cvtpk(v0, v1), w1 = cvtpk(v2, v3);
                int u0 = wc + cb * 16 + lh * 4;
                int sg = (u0 >> 3) ^ (prow & 15);
                unsigned int* dst = (unsigned int*)(X + prow * 256 + sg * 8 + (u0 & 7));
                dst[0] = w0; dst[1] = w1;
            }
        }
        __syncthreads();
    }

    if (wid == 0) {
        f32x4 acc3[4];
        #pragma unroll
        for (int rb = 0; rb < 4; ++rb) acc3[rb] = (f32x4){0.f,0.f,0.f,0.f};
        #pragma unroll
        for (int kk = 0; kk < 8; ++kk) {
            bf16x8 wfrag = *(const bf16x8*)(wt3 + (size_t)kk * 512 + lr * 32 + lh * 8);
            #pragma unroll
            for (int rb = 0; rb < 4; ++rb) {
                int row = rb * 16 + lr;
                int sg = (kk * 4 + lh) ^ (row & 15);
                bf16x8 af = *(const bf16x8*)(X + row * 256 + sg * 8);
                acc3[rb] = __builtin_amdgcn_mfma_f32_16x16x32_bf16(wfrag, af, acc3[rb], 0, 0, 0);
            }
        }
        #pragma unroll
        for (int rb = 0; rb < 4; ++rb) {
            int prow = rb * 16 + lr;
            #pragma unroll
            for (int reg = 0; reg < 4; ++reg) {
                int u = lh * 4 + reg;
                if (u < 10) out[(size_t)(r0 + prow) * 10 + u] = acc3[rb][reg] + f3b[u];
            }
        }
    }
}

// ---------- launch ----------
extern "C" void kernel_launch(void* const* d_in, const int* in_sizes, int n_in,
                              void* d_out, int out_size, void* d_ws, size_t ws_size,
                              hipStream_t stream)
{
    const float* im  = (const float*)d_in[0];
    const float* q   = (const float*)d_in[1];
    const float* c1w = (const float*)d_in[2];
    const float* c1b = (const float*)d_in[3];
    const float* n1g = (const float*)d_in[4];
    const float* n1b = (const float*)d_in[5];
    const float* c2w = (const float*)d_in[6];
    const float* c2b = (const float*)d_in[7];
    const float* n2g = (const float*)d_in[8];
    const float* n2b = (const float*)d_in[9];
    const float* c3w = (const float*)d_in[10];
    const float* c3b = (const float*)d_in[11];
    const float* n3g = (const float*)d_in[12];
    const float* n3b = (const float*)d_in[13];
    const float* c4w = (const float*)d_in[14];
    const float* c4b = (const float*)d_in[15];
    const float* n4g = (const float*)d_in[16];
    const float* n4b = (const float*)d_in[17];
    const float* g1w = (const float*)d_in[18];
    const float* g1b = (const float*)d_in[19];
    const float* g2w = (const float*)d_in[20];
    const float* g2b = (const float*)d_in[21];
    const float* g3w = (const float*)d_in[22];
    const float* g3b = (const float*)d_in[23];
    const float* g4w = (const float*)d_in[24];
    const float* g4b = (const float*)d_in[25];
    const float* f1w = (const float*)d_in[26];
    const float* f1b = (const float*)d_in[27];
    const float* f2w = (const float*)d_in[28];
    const float* f2b = (const float*)d_in[29];
    const float* f3w = (const float*)d_in[30];
    const float* f3b = (const float*)d_in[31];

    char* ws = (char*)d_ws;
    size_t off = 0;
    auto alloc = [&](size_t bytes) -> void* {
        void* p = ws + off;
        off += (bytes + 255) & ~(size_t)255;
        return p;
    };
    unsigned short* A   = (unsigned short*)alloc(3276800ull * 2);
    unsigned short* Bv  = (unsigned short*)alloc(3276800ull * 2);
    unsigned short* Xf  = (unsigned short*)alloc(409600ull * 2);
    unsigned short* W1t = (unsigned short*)alloc(16384ull * 2);
    unsigned short* wg2 = (unsigned short*)alloc(65536ull * 2);
    unsigned short* wg3 = (unsigned short*)alloc(65536ull * 2);
    unsigned short* wg4 = (unsigned short*)alloc(65536ull * 2);
    unsigned short* wf1 = (unsigned short*)alloc(65536ull * 2);
    unsigned short* wf2 = (unsigned short*)alloc(65536ull * 2);
    unsigned short* wt3 = (unsigned short*)alloc(4096ull * 2);
    float* Cq  = (float*)alloc(131072ull * 4);
    float* xg  = (float*)alloc(131072ull * 4);
    float* wc1 = (float*)alloc(648ull * 4);
    float* wc2 = (float*)alloc(5184ull * 4);
    float* wc3 = (float*)alloc(5184ull * 4);
    float* wc4 = (float*)alloc(5184ull * 4);

    prep_misc_kernel<<<2448, 256, 0, stream>>>(g1w, g1b, g2w, g3w, g4w, f1w, f2w, f3w, q,
                                               c1w, c2w, c3w, c4w,
                                               W1t, wg2, wg3, wg4, wf1, wf2, wt3, xg, Cq,
                                               wc1, wc2, wc3, wc4);

    conv_fused_kernel<<<512, 1024, 115200, stream>>>(im,
        wc1, c1b, n1g, n1b, wc2, c2b, n2g, n2b,
        wc3, c3b, n3g, n3b, wc4, c4b, n4g, n4b, Xf);

    prep_gemm_kernel<<<200, 512, 0, stream>>>(Xf, W1t, Cq, A, Bv);

    gmlp_kernel<<<512 * 5, 256, 0, stream>>>(A, Bv, wg2, g2b, wg3, g3b, wg4, g4b, xg);

    fc_mfma_kernel<<<8, 256, 0, stream>>>(xg, wf1, f1b, wf2, f2b, wt3, f3b, (float*)d_out);
}

// Round 11
// 275.532 us; speedup vs baseline: 1.7821x; 1.3342x over previous
//
#include <hip/hip_runtime.h>
#include <stdint.h>

typedef short     bf16x8  __attribute__((ext_vector_type(8)));
typedef float     f32x4   __attribute__((ext_vector_type(4)));
typedef unsigned short u16x8 __attribute__((ext_vector_type(8)));
typedef unsigned short u16x4 __attribute__((ext_vector_type(4)));
typedef unsigned int   u32x4 __attribute__((ext_vector_type(4)));

__device__ __forceinline__ float bf2f(unsigned short u) {
    union { unsigned int i; float f; } v; v.i = ((unsigned int)u) << 16; return v.f;
}
__device__ __forceinline__ unsigned short f2bf(float f) {
    union { float f; unsigned int i; } v; v.f = f;
    unsigned int x = v.i;
    return (unsigned short)((x + 0x7fffu + ((x >> 16) & 1u)) >> 16);
}
__device__ __forceinline__ unsigned int cvtpk(float lo, float hi) {
    unsigned int r;
    asm("v_cvt_pk_bf16_f32 %0, %1, %2" : "=v"(r) : "v"(lo), "v"(hi));
    return r;
}

// ---------- 24->24 stride-2 conv step, LDS -> LDS, NHWC, WAVE-uniform channel split ----------
// wc layout [kb][ci][co]. Wave-task = (pixel chunk of 64, channel group of NCO).
// co0 forced to SGPR via readfirstlane -> weight/bias reads are consecutive s_loads.
template<int NCO>
__device__ __forceinline__ void convs24_wave(const unsigned short* __restrict__ in, int H,
                                             unsigned short* __restrict__ out, int OH,
                                             const float* __restrict__ wc, const float* __restrict__ bias,
                                             const float* __restrict__ bng, const float* __restrict__ bnb,
                                             int wid, int lane, int nw)
{
    const int per = 24 / NCO;
    int npix = OH * OH;
    int nchunk = (npix + 63) >> 6;
    int ntask = nchunk * per;
    for (int wt = wid; wt < ntask; wt += nw) {
        int sc = wt % per;
        int chunk = wt / per;
        int co0 = __builtin_amdgcn_readfirstlane(sc * NCO);
        int p = chunk * 64 + lane;
        bool act = p < npix;
        int pc = act ? p : npix - 1;
        int ow = pc % OH, oh = pc / OH;
        float acc[NCO];
        #pragma unroll
        for (int c = 0; c < NCO; ++c) acc[c] = 0.f;
        int ih0 = 2 * oh - 1, iw0 = 2 * ow - 1;
        #pragma unroll 1
        for (int ky = 0; ky < 3; ++ky) {
            int ih = ih0 + ky; if (ih < 0) continue;
            #pragma unroll 1
            for (int kx = 0; kx < 3; ++kx) {
                int iw = iw0 + kx; if (iw < 0) continue;
                const unsigned short* pp = in + (ih * H + iw) * 24;
                u16x4 v[6];
                #pragma unroll
                for (int m = 0; m < 6; ++m) v[m] = *(const u16x4*)(pp + m * 4);
                float x[24];
                #pragma unroll
                for (int m = 0; m < 6; ++m)
                    #pragma unroll
                    for (int e = 0; e < 4; ++e) x[m * 4 + e] = bf2f(v[m][e]);
                int kb = ky * 3 + kx;
                const float* wk = wc + kb * 576 + co0;
                #pragma unroll
                for (int ci = 0; ci < 24; ++ci) {
                    float xv = x[ci];
                    #pragma unroll
                    for (int c = 0; c < NCO; ++c)
                        acc[c] += xv * wk[ci * 24 + c];      // wk[..]: wave-uniform s_load
                }
            }
        }
        if (act) {
            unsigned short* op = out + p * 24 + co0;
            #pragma unroll
            for (int c4i = 0; c4i < NCO / 4; ++c4i) {
                u16x4 o;
                #pragma unroll
                for (int e = 0; e < 4; ++e) {
                    int co = co0 + c4i * 4 + e;
                    float scale = bng[co] * 0.9999950000374997f;
                    o[e] = f2bf((acc[c4i * 4 + e] + bias[co]) * scale + bnb[co]);
                }
                *(u16x4*)(op + c4i * 4) = o;
            }
        }
    }
}

// ---------- fully fused conv1..conv4: one block per image; writes only Xf ----------
__global__ __launch_bounds__(1024) void conv_fused_kernel(
    const float* __restrict__ im,
    const float* __restrict__ wc1, const float* __restrict__ c1b,
    const float* __restrict__ n1g, const float* __restrict__ n1b,
    const float* __restrict__ wc2, const float* __restrict__ c2b,
    const float* __restrict__ n2g, const float* __restrict__ n2b,
    const float* __restrict__ wc3, const float* __restrict__ c3b,
    const float* __restrict__ n3g, const float* __restrict__ n3b,
    const float* __restrict__ wc4, const float* __restrict__ c4b,
    const float* __restrict__ n4g, const float* __restrict__ n4b,
    unsigned short* __restrict__ Xf)
{
    extern __shared__ unsigned short smem[];
    unsigned short* bufA = smem;            // 19200: im bf16; later c2 (9600)
    unsigned short* bufB = smem + 19200;    // 38400: c1; later c3 (2400)
    int b = blockIdx.x, t = threadIdx.x;

    // stage image (fp32 -> bf16, coalesced)
    const float* ip = im + (size_t)b * 19200;
    for (int i = t; i < 19200; i += 1024) bufA[i] = f2bf(ip[i]);
    __syncthreads();

    // conv1: bufA [3][80][80] -> bufB [40][40][24]; wc1 [k][co], k uniform -> s_loads
    for (int p = t; p < 1600; p += 1024) {
        int ow = p % 40, oh = p / 40;
        float acc[24];
        #pragma unroll
        for (int co = 0; co < 24; ++co) acc[co] = 0.f;
        int ih0 = 2 * oh - 1, iw0 = 2 * ow - 1;
        #pragma unroll 1
        for (int ci = 0; ci < 3; ++ci) {
            #pragma unroll 1
            for (int ky = 0; ky < 3; ++ky) {
                int ih = ih0 + ky; if (ih < 0) continue;
                #pragma unroll 1
                for (int kx = 0; kx < 3; ++kx) {
                    int iw = iw0 + kx; if (iw < 0) continue;
                    float x = bf2f(bufA[ci * 6400 + ih * 80 + iw]);
                    const float* wk = wc1 + (ci * 9 + ky * 3 + kx) * 24;
                    #pragma unroll
                    for (int co = 0; co < 24; ++co) acc[co] += x * wk[co];
                }
            }
        }
        unsigned short* op = bufB + p * 24;
        u16x4 o[6];
        #pragma unroll
        for (int co = 0; co < 24; ++co) {
            float scale = n1g[co] * 0.9999950000374997f;
            o[co >> 2][co & 3] = f2bf((acc[co] + c1b[co]) * scale + n1b[co]);
        }
        #pragma unroll
        for (int m = 0; m < 6; ++m) *(u16x4*)(op + m * 4) = o[m];
    }
    __syncthreads();

    int wid = t >> 6, lane = t & 63;

    // conv2: bufB[40] -> bufA[20]; 7 chunks x 2 groups = 14 wave-tasks
    convs24_wave<12>(bufB, 40, bufA, 20, wc2, c2b, n2g, n2b, wid, lane, 16);
    __syncthreads();
    // conv3: bufA[20] -> bufB[10]; 2 chunks x 3 groups = 6 wave-tasks
    convs24_wave<8>(bufA, 20, bufB, 10, wc3, c3b, n3g, n3b, wid, lane, 16);
    __syncthreads();

    // conv4: bufB[10][10][24] -> Xf; 3 wave-tasks (NCO=8), coords from task 0
    for (int wt = wid; wt < 3; wt += 16) {
        int co0 = __builtin_amdgcn_readfirstlane(wt * 8);
        int p = lane;
        bool act = p < 25;
        int pc = act ? p : 24;
        int ow = pc % 5, oh = pc / 5;
        float acc[8];
        #pragma unroll
        for (int c = 0; c < 8; ++c) acc[c] = 0.f;
        int ih0 = 2 * oh - 1, iw0 = 2 * ow - 1;
        #pragma unroll 1
        for (int ky = 0; ky < 3; ++ky) {
            int ih = ih0 + ky; if (ih < 0) continue;
            #pragma unroll 1
            for (int kx = 0; kx < 3; ++kx) {
                int iw = iw0 + kx; if (iw < 0) continue;
                const unsigned short* pp = bufB + (ih * 10 + iw) * 24;
                u16x4 v[6];
                #pragma unroll
                for (int m = 0; m < 6; ++m) v[m] = *(const u16x4*)(pp + m * 4);
                float x[24];
                #pragma unroll
                for (int m = 0; m < 6; ++m)
                    #pragma unroll
                    for (int e = 0; e < 4; ++e) x[m * 4 + e] = bf2f(v[m][e]);
                int kb = ky * 3 + kx;
                const float* wk = wc4 + kb * 576 + co0;
                #pragma unroll
                for (int ci = 0; ci < 24; ++ci) {
                    float xv = x[ci];
                    #pragma unroll
                    for (int c = 0; c < 8; ++c)
                        acc[c] += xv * wk[ci * 24 + c];
                }
            }
        }
        if (act) {
            unsigned short* op = Xf + ((size_t)b * 25 + p) * 32 + co0;
            #pragma unroll
            for (int c4i = 0; c4i < 2; ++c4i) {
                u16x4 o;
                #pragma unroll
                for (int e = 0; e < 4; ++e) {
                    int co = co0 + c4i * 4 + e;
                    float scale = n4g[co] * 0.9999950000374997f;
                    o[e] = f2bf((acc[c4i * 4 + e] + c4b[co]) * scale + n4b[co]);
                }
                *(u16x4*)(op + c4i * 4) = o;
            }
            if (co0 == 0) {
                u16x8 o;
                o[0] = f2bf((oh - 2) * 0.5f);
                o[1] = f2bf((ow - 2) * 0.5f);
                #pragma unroll
                for (int e = 2; e < 8; ++e) o[e] = 0;
                *(u16x8*)(Xf + ((size_t)b * 25 + p) * 32 + 24) = o;
            }
        }
    }
}

// ---------- prep_misc: W1t + wt(g2,g3,g4,f1,f2) + wt3(f3) + zero(xg) + Cq + conv wc ----------
__global__ void prep_misc_kernel(const float* __restrict__ g1w, const float* __restrict__ g1b,
                                 const float* __restrict__ g2w, const float* __restrict__ g3w,
                                 const float* __restrict__ g4w, const float* __restrict__ f1w,
                                 const float* __restrict__ f2w, const float* __restrict__ f3w,
                                 const float* __restrict__ q,
                                 const float* __restrict__ c1w, const float* __restrict__ c2w,
                                 const float* __restrict__ c3w, const float* __restrict__ c4w,
                                 unsigned short* __restrict__ W1t,
                                 unsigned short* __restrict__ wg2, unsigned short* __restrict__ wg3,
                                 unsigned short* __restrict__ wg4, unsigned short* __restrict__ wf1,
                                 unsigned short* __restrict__ wf2, unsigned short* __restrict__ wt3,
                                 float* __restrict__ xg, float* __restrict__ Cq,
                                 float* __restrict__ wc1, float* __restrict__ wc2,
                                 float* __restrict__ wc3, float* __restrict__ wc4)
{
    int blk = blockIdx.x, t = threadIdx.x;
    if (blk < 64) {                                     // W1t [512][32]
        int i = blk * 256 + t;
        int u = i >> 5, k = i & 31;
        float v = 0.f;
        if (k < 26) v = (u < 256) ? g1w[u * 63 + k] : g1w[(u - 256) * 63 + 26 + k];
        W1t[i] = f2bf(v);
    } else if (blk < 1344) {                            // wt layout [kk][u][32]
        int s = blk - 64;
        int which = s >> 8;
        int i = (s & 255) * 256 + t;
        int kin = i & 31, u = (i >> 5) & 255, kk = i >> 13;
        const float* w = (which == 0) ? g2w : (which == 1) ? g3w :
                         (which == 2) ? g4w : (which == 3) ? f1w : f2w;
        unsigned short* wt = (which == 0) ? wg2 : (which == 1) ? wg3 :
                             (which == 2) ? wg4 : (which == 3) ? wf1 : wf2;
        wt[i] = f2bf(w[u * 256 + kk * 32 + kin]);
    } else if (blk < 1360) {                            // wt3 [kk][16][32], u>=10 zero
        int i = (blk - 1344) * 256 + t;
        int kin = i & 31, u = (i >> 5) & 15, kk = i >> 9;
        wt3[i] = (u < 10) ? f2bf(f3w[u * 256 + kk * 32 + kin]) : 0;
    } else if (blk < 1872) {                            // zero xg
        xg[(size_t)(blk - 1360) * 256 + t] = 0.f;
    } else if (blk < 2384) {                            // Cq[b][u]
        int b = blk - 1872, u = t;
        float acc = g1b[u];
        #pragma unroll
        for (int k = 0; k < 11; ++k)
            acc += g1w[u * 63 + 52 + k] * q[b * 11 + k];
        Cq[(size_t)b * 256 + u] = acc;
    } else {                                            // conv weight transposes
        int i = (blk - 2384) * 256 + t;
        if (i < 648) {                                  // wc1[k][co] = c1w[co][k]
            int k = i / 24, co = i % 24;
            wc1[i] = c1w[co * 27 + k];
        } else if (i < 16200) {                         // wcN[kb][ci][co] = cNw[co][ci][kb]
            int j = i - 648;
            int which = j / 5184; j %= 5184;
            int kb = j / 576, r = j % 576, ci = r / 24, co = r % 24;
            const float* src = (which == 0) ? c2w : (which == 1) ? c3w : c4w;
            float* dst = (which == 0) ? wc2 : (which == 1) ? wc3 : wc4;
            dst[j] = src[co * 216 + ci * 9 + kb];
        }
    }
}

// ---------- prep GEMM: Xf[12800x32] x W1t -> A(+Cq folded), Bv bf16 ----------
__global__ __launch_bounds__(512) void prep_gemm_kernel(
    const unsigned short* __restrict__ Xf, const unsigned short* __restrict__ W1t,
    const float* __restrict__ Cq,
    unsigned short* __restrict__ A, unsigned short* __restrict__ Bv)
{
    int t = threadIdx.x, w8 = t >> 6, lane = t & 63;
    int rg = w8 & 3, cg = w8 >> 2;
    int lr = lane & 15, lh = lane >> 4;
    int row = blockIdx.x * 64 + rg * 16 + lr;
    bf16x8 af = *(const bf16x8*)(Xf + (size_t)row * 32 + lh * 8);
    f32x4 acc[16];
    #pragma unroll
    for (int ct = 0; ct < 16; ++ct) {
        int c0 = cg * 256 + ct * 16;
        bf16x8 bf = *(const bf16x8*)(W1t + (size_t)(c0 + lr) * 32 + lh * 8);
        acc[ct] = __builtin_amdgcn_mfma_f32_16x16x32_bf16(af, bf, (f32x4){0.f,0.f,0.f,0.f}, 0, 0, 0);
    }
    unsigned short* dst = (cg == 0) ? A : Bv;
    #pragma unroll
    for (int ct = 0; ct < 16; ++ct) {
        int col = ct * 16 + lr;
        #pragma unroll
        for (int reg = 0; reg < 4; ++reg) {
            int orow = blockIdx.x * 64 + rg * 16 + lh * 4 + reg;
            float v = acc[ct][reg];
            if (cg == 0) v += Cq[(orow / 25) * 256 + col];
            dst[(size_t)orow * 256 + col] = f2bf(v);
        }
    }
}

// ---------- gemm over 128 rows: wave = 128 rows x 64 cols ----------
template<bool SWAP>
__device__ __forceinline__ void gemm_k128(const unsigned short* __restrict__ W,
                                          const unsigned short* X,
                                          int lr, int lh, int wc, f32x4 acc[8][4])
{
    bf16x8 bcur[4], bnxt[4];
    #pragma unroll
    for (int cb = 0; cb < 4; ++cb)
        bcur[cb] = *(const bf16x8*)(W + (wc + cb * 16 + lr) * 32 + lh * 8);
    #pragma unroll
    for (int kk = 0; kk < 8; ++kk) {
        if (kk < 7) {
            #pragma unroll
            for (int cb = 0; cb < 4; ++cb)
                bnxt[cb] = *(const bf16x8*)(W + (size_t)(kk + 1) * 8192 + (wc + cb * 16 + lr) * 32 + lh * 8);
        }
        #pragma unroll
        for (int rb = 0; rb < 8; ++rb) {
            int row = rb * 16 + lr;
            int sg = (kk * 4 + lh) ^ (row & 15);
            bf16x8 af = *(const bf16x8*)(X + row * 256 + sg * 8);
            #pragma unroll
            for (int cb = 0; cb < 4; ++cb)
                acc[rb][cb] = SWAP
                    ? __builtin_amdgcn_mfma_f32_16x16x32_bf16(bcur[cb], af, acc[rb][cb], 0, 0, 0)
                    : __builtin_amdgcn_mfma_f32_16x16x32_bf16(af, bcur[cb], acc[rb][cb], 0, 0, 0);
        }
        #pragma unroll
        for (int cb = 0; cb < 4; ++cb) bcur[cb] = bnxt[cb];
    }
}

// ---------- gemm over 64 rows (fc) ----------
template<bool SWAP>
__device__ __forceinline__ void gemm_k64(const unsigned short* __restrict__ W,
                                         const unsigned short* X,
                                         int lr, int lh, int wc, f32x4 acc[4][4])
{
    bf16x8 bcur[4], bnxt[4];
    #pragma unroll
    for (int cb = 0; cb < 4; ++cb)
        bcur[cb] = *(const bf16x8*)(W + (wc + cb * 16 + lr) * 32 + lh * 8);
    #pragma unroll
    for (int kk = 0; kk < 8; ++kk) {
        if (kk < 7) {
            #pragma unroll
            for (int cb = 0; cb < 4; ++cb)
                bnxt[cb] = *(const bf16x8*)(W + (size_t)(kk + 1) * 8192 + (wc + cb * 16 + lr) * 32 + lh * 8);
        }
        #pragma unroll
        for (int rb = 0; rb < 4; ++rb) {
            int row = rb * 16 + lr;
            int sg = (kk * 4 + lh) ^ (row & 15);
            bf16x8 af = *(const bf16x8*)(X + row * 256 + sg * 8);
            #pragma unroll
            for (int cb = 0; cb < 4; ++cb)
                acc[rb][cb] = SWAP
                    ? __builtin_amdgcn_mfma_f32_16x16x32_bf16(bcur[cb], af, acc[rb][cb], 0, 0, 0)
                    : __builtin_amdgcn_mfma_f32_16x16x32_bf16(af, bcur[cb], acc[rb][cb], 0, 0, 0);
        }
        #pragma unroll
        for (int cb = 0; cb < 4; ++cb) bcur[cb] = bnxt[cb];
    }
}

// ---------- fused g2/g3/g4 + pair-sum; 128-row tile, 64KB LDS, 4 waves ----------
__global__ __launch_bounds__(256, 2) void gmlp_kernel(
    const unsigned short* __restrict__ A, const unsigned short* __restrict__ Bv,
    const unsigned short* __restrict__ w2, const float* __restrict__ b2,
    const unsigned short* __restrict__ w3, const float* __restrict__ b3,
    const unsigned short* __restrict__ w4, const float* __restrict__ b4,
    float* __restrict__ xg)
{
    __shared__ unsigned short X[128 * 256];   // 64 KB

    int blk  = blockIdx.x;
    int b    = blk / 5;
    int tile = blk % 5;
    int row0 = tile * 128;
    int t = threadIdx.x;

    {
        int r = t >> 1, half = t & 1;
        int prow = row0 + r;
        if (prow < 625) {
            int i = prow / 25, j = prow % 25;
            const unsigned short* Ap = A  + ((size_t)b * 25 + j) * 256;
            const unsigned short* Bp = Bv + ((size_t)b * 25 + i) * 256;
            #pragma unroll
            for (int k = 0; k < 16; ++k) {
                int g = half + 2 * k;
                int c0 = g * 8;
                u16x8 av = *(const u16x8*)(Ap + c0);
                u16x8 bv = *(const u16x8*)(Bp + c0);
                float v[8];
                #pragma unroll
                for (int e = 0; e < 8; ++e)
                    v[e] = fmaxf(bf2f(av[e]) + bf2f(bv[e]), 0.f);
                u32x4 o = { cvtpk(v[0], v[1]), cvtpk(v[2], v[3]),
                            cvtpk(v[4], v[5]), cvtpk(v[6], v[7]) };
                int sg = g ^ (r & 15);
                *(u32x4*)(X + r * 256 + sg * 8) = o;
            }
        } else {
            u32x4 z = {0, 0, 0, 0};
            #pragma unroll
            for (int k = 0; k < 16; ++k) {
                int g = half + 2 * k;
                int sg = g ^ (r & 15);
                *(u32x4*)(X + r * 256 + sg * 8) = z;
            }
        }
    }
    __syncthreads();

    int wid = t >> 6, lane = t & 63;
    int wc = wid * 64;
    int lr = lane & 15, lh = lane >> 4;

    const unsigned short* Wsw[2] = { w2, w3 };
    const float* Bsw[2] = { b2, b3 };
    #pragma unroll 1
    for (int L = 0; L < 2; ++L) {
        f32x4 acc[8][4];
        #pragma unroll
        for (int rb = 0; rb < 8; ++rb)
            #pragma unroll
            for (int cb = 0; cb < 4; ++cb) acc[rb][cb] = (f32x4){0.f,0.f,0.f,0.f};
        gemm_k128<true>(Wsw[L], X, lr, lh, wc, acc);

        f32x4 bsw[4];
        #pragma unroll
        for (int cb = 0; cb < 4; ++cb)
            bsw[cb] = *(const f32x4*)(Bsw[L] + wc + cb * 16 + lh * 4);

        __syncthreads();
        #pragma unroll
        for (int rb = 0; rb < 8; ++rb) {
            int prow = rb * 16 + lr;
            #pragma unroll
            for (int cb = 0; cb < 4; ++cb) {
                float v0 = fmaxf(acc[rb][cb][0] + bsw[cb][0], 0.f);
                float v1 = fmaxf(acc[rb][cb][1] + bsw[cb][1], 0.f);
                float v2 = fmaxf(acc[rb][cb][2] + bsw[cb][2], 0.f);
                float v3 = fmaxf(acc[rb][cb][3] + bsw[cb][3], 0.f);
                unsigned int w0 = cvtpk(v0, v1), w1 = cvtpk(v2, v3);
                int u0 = wc + cb * 16 + lh * 4;
                int sg = (u0 >> 3) ^ (prow & 15);
                unsigned int* dst = (unsigned int*)(X + prow * 256 + sg * 8 + (u0 & 7));
                dst[0] = w0; dst[1] = w1;
            }
        }
        __syncthreads();
    }

    {
        f32x4 acc[8][4];
        #pragma unroll
        for (int rb = 0; rb < 8; ++rb)
            #pragma unroll
            for (int cb = 0; cb < 4; ++cb) acc[rb][cb] = (f32x4){0.f,0.f,0.f,0.f};
        gemm_k128<false>(w4, X, lr, lh, wc, acc);

        float bias[4];
        #pragma unroll
        for (int cb = 0; cb < 4; ++cb) bias[cb] = b4[wc + cb * 16 + lr];

        float csum[4] = {0.f, 0.f, 0.f, 0.f};
        #pragma unroll
        for (int rb = 0; rb < 8; ++rb) {
            #pragma unroll
            for (int reg = 0; reg < 4; ++reg) {
                int rowloc = rb * 16 + lh * 4 + reg;
                bool valid = (row0 + rowloc) < 625;
                #pragma unroll
                for (int cb = 0; cb < 4; ++cb) {
                    float v = fmaxf(acc[rb][cb][reg] + bias[cb], 0.f);
                    if (valid) csum[cb] += v;
                }
            }
        }
        #pragma unroll
        for (int cb = 0; cb < 4; ++cb) {
            csum[cb] += __shfl_xor(csum[cb], 16);
            csum[cb] += __shfl_xor(csum[cb], 32);
        }
        if (lh == 0) {
            #pragma unroll
            for (int cb = 0; cb < 4; ++cb)
                atomicAdd(&xg[(size_t)b * 256 + wc + cb * 16 + lr], csum[cb]);
        }
    }
}

// ---------- fc via MFMA: 8 blocks x 64 batch rows; f1,f2 in-place in LDS; f3 on wave0 ----------
__global__ __launch_bounds__(256) void fc_mfma_kernel(
    const float* __restrict__ xg,
    const unsigned short* __restrict__ wf1, const float* __restrict__ f1b,
    const unsigned short* __restrict__ wf2, const float* __restrict__ f2b,
    const unsigned short* __restrict__ wt3, const float* __restrict__ f3b,
    float* __restrict__ out)
{
    __shared__ unsigned short X[64 * 256];   // 32 KB
    int r0 = blockIdx.x * 64;
    int t = threadIdx.x;

    {
        int r = t >> 2, quad = t & 3;
        const float* Sp = xg + (size_t)(r0 + r) * 256;
        #pragma unroll
        for (int k = 0; k < 8; ++k) {
            int g = quad + 4 * k;
            int c0 = g * 8;
            f32x4 a0 = *(const f32x4*)(Sp + c0);
            f32x4 a1 = *(const f32x4*)(Sp + c0 + 4);
            u32x4 o = { cvtpk(a0[0], a0[1]), cvtpk(a0[2], a0[3]),
                        cvtpk(a1[0], a1[1]), cvtpk(a1[2], a1[3]) };
            int sg = g ^ (r & 15);
            *(u32x4*)(X + r * 256 + sg * 8) = o;
        }
    }
    __syncthreads();

    int wid = t >> 6, lane = t & 63;
    int wc = wid * 64;
    int lr = lane & 15, lh = lane >> 4;

    const unsigned short* Ws[2] = { wf1, wf2 };
    const float* Bs[2] = { f1b, f2b };
    #pragma unroll 1
    for (int L = 0; L < 2; ++L) {
        f32x4 acc[4][4];
        #pragma unroll
        for (int rb = 0; rb < 4; ++rb)
            #pragma unroll
            for (int cb = 0; cb < 4; ++cb) acc[rb][cb] = (f32x4){0.f,0.f,0.f,0.f};
        gemm_k64<true>(Ws[L], X, lr, lh, wc, acc);

        f32x4 bsw[4];
        #pragma unroll
        for (int cb = 0; cb < 4; ++cb)
            bsw[cb] = *(const f32x4*)(Bs[L] + wc + cb * 16 + lh * 4);

        __syncthreads();
        #pragma unroll
        for (int rb = 0; rb < 4; ++rb) {
            int prow = rb * 16 + lr;
            #pragma unroll
            for (int cb = 0; cb < 4; ++cb) {
                float v0 = fmaxf(acc[rb][cb][0] + bsw[cb][0], 0.f);
                float v1 = fmaxf(acc[rb][cb][1] + bsw[cb][1], 0.f);
                float v2 = fmaxf(acc[rb][cb][2] + bsw[cb][2], 0.f);
                float v3 = fmaxf(acc[rb][cb][3] + bsw[cb][3], 0.f);
                unsigned int w0 = cvtpk(v0, v1), w1 = cvtpk(v2, v3);
                int u0 = wc + cb * 16 + lh * 4;
                int sg = (u0 >> 3) ^ (prow & 15);
                unsigned int* dst = (unsigned int*)(X + prow * 256 + sg * 8 + (u0 & 7));
                dst[0] = w0; dst[1] = w1;
            }
        }
        __syncthreads();
    }

    if (wid == 0) {
        f32x4 acc3[4];
        #pragma unroll
        for (int rb = 0; rb < 4; ++rb) acc3[rb] = (f32x4){0.f,0.f,0.f,0.f};
        #pragma unroll
        for (int kk = 0; kk < 8; ++kk) {
            bf16x8 wfrag = *(const bf16x8*)(wt3 + (size_t)kk * 512 + lr * 32 + lh * 8);
            #pragma unroll
            for (int rb = 0; rb < 4; ++rb) {
                int row = rb * 16 + lr;
                int sg = (kk * 4 + lh) ^ (row & 15);
                bf16x8 af = *(const bf16x8*)(X + row * 256 + sg * 8);
                acc3[rb] = __builtin_amdgcn_mfma_f32_16x16x32_bf16(wfrag, af, acc3[rb], 0, 0, 0);
            }
        }
        #pragma unroll
        for (int rb = 0; rb < 4; ++rb) {
            int prow = rb * 16 + lr;
            #pragma unroll
            for (int reg = 0; reg < 4; ++reg) {
                int u = lh * 4 + reg;
                if (u < 10) out[(size_t)(r0 + prow) * 10 + u] = acc3[rb][reg] + f3b[u];
            }
        }
    }
}

// ---------- launch ----------
extern "C" void kernel_launch(void* const* d_in, const int* in_sizes, int n_in,
                              void* d_out, int out_size, void* d_ws, size_t ws_size,
                              hipStream_t stream)
{
    const float* im  = (const float*)d_in[0];
    const float* q   = (const float*)d_in[1];
    const float* c1w = (const float*)d_in[2];
    const float* c1b = (const float*)d_in[3];
    const float* n1g = (const float*)d_in[4];
    const float* n1b = (const float*)d_in[5];
    const float* c2w = (const float*)d_in[6];
    const float* c2b = (const float*)d_in[7];
    const float* n2g = (const float*)d_in[8];
    const float* n2b = (const float*)d_in[9];
    const float* c3w = (const float*)d_in[10];
    const float* c3b = (const float*)d_in[11];
    const float* n3g = (const float*)d_in[12];
    const float* n3b = (const float*)d_in[13];
    const float* c4w = (const float*)d_in[14];
    const float* c4b = (const float*)d_in[15];
    const float* n4g = (const float*)d_in[16];
    const float* n4b = (const float*)d_in[17];
    const float* g1w = (const float*)d_in[18];
    const float* g1b = (const float*)d_in[19];
    const float* g2w = (const float*)d_in[20];
    const float* g2b = (const float*)d_in[21];
    const float* g3w = (const float*)d_in[22];
    const float* g3b = (const float*)d_in[23];
    const float* g4w = (const float*)d_in[24];
    const float* g4b = (const float*)d_in[25];
    const float* f1w = (const float*)d_in[26];
    const float* f1b = (const float*)d_in[27];
    const float* f2w = (const float*)d_in[28];
    const float* f2b = (const float*)d_in[29];
    const float* f3w = (const float*)d_in[30];
    const float* f3b = (const float*)d_in[31];

    char* ws = (char*)d_ws;
    size_t off = 0;
    auto alloc = [&](size_t bytes) -> void* {
        void* p = ws + off;
        off += (bytes + 255) & ~(size_t)255;
        return p;
    };
    unsigned short* A   = (unsigned short*)alloc(3276800ull * 2);
    unsigned short* Bv  = (unsigned short*)alloc(3276800ull * 2);
    unsigned short* Xf  = (unsigned short*)alloc(409600ull * 2);
    unsigned short* W1t = (unsigned short*)alloc(16384ull * 2);
    unsigned short* wg2 = (unsigned short*)alloc(65536ull * 2);
    unsigned short* wg3 = (unsigned short*)alloc(65536ull * 2);
    unsigned short* wg4 = (unsigned short*)alloc(65536ull * 2);
    unsigned short* wf1 = (unsigned short*)alloc(65536ull * 2);
    unsigned short* wf2 = (unsigned short*)alloc(65536ull * 2);
    unsigned short* wt3 = (unsigned short*)alloc(4096ull * 2);
    float* Cq  = (float*)alloc(131072ull * 4);
    float* xg  = (float*)alloc(131072ull * 4);
    float* wc1 = (float*)alloc(648ull * 4);
    float* wc2 = (float*)alloc(5184ull * 4);
    float* wc3 = (float*)alloc(5184ull * 4);
    float* wc4 = (float*)alloc(5184ull * 4);

    prep_misc_kernel<<<2448, 256, 0, stream>>>(g1w, g1b, g2w, g3w, g4w, f1w, f2w, f3w, q,
                                               c1w, c2w, c3w, c4w,
                                               W1t, wg2, wg3, wg4, wf1, wf2, wt3, xg, Cq,
                                               wc1, wc2, wc3, wc4);

    conv_fused_kernel<<<512, 1024, 115200, stream>>>(im,
        wc1, c1b, n1g, n1b, wc2, c2b, n2g, n2b,
        wc3, c3b, n3g, n3b, wc4, c4b, n4g, n4b, Xf);

    prep_gemm_kernel<<<200, 512, 0, stream>>>(Xf, W1t, Cq, A, Bv);

    gmlp_kernel<<<512 * 5, 256, 0, stream>>>(A, Bv, wg2, g2b, wg3, g3b, wg4, g4b, xg);

    fc_mfma_kernel<<<8, 256, 0, stream>>>(xg, wf1, f1b, wf2, f2b, wt3, f3b, (float*)d_out);
}

// Round 12
// 266.966 us; speedup vs baseline: 1.8393x; 1.0321x over previous
//
#include <hip/hip_runtime.h>
#include <stdint.h>

typedef short     bf16x8  __attribute__((ext_vector_type(8)));
typedef float     f32x4   __attribute__((ext_vector_type(4)));
typedef unsigned short u16x8 __attribute__((ext_vector_type(8)));
typedef unsigned short u16x4 __attribute__((ext_vector_type(4)));
typedef unsigned int   u32x4 __attribute__((ext_vector_type(4)));

__device__ __forceinline__ float bf2f(unsigned short u) {
    union { unsigned int i; float f; } v; v.i = ((unsigned int)u) << 16; return v.f;
}
__device__ __forceinline__ unsigned short f2bf(float f) {
    union { float f; unsigned int i; } v; v.f = f;
    unsigned int x = v.i;
    return (unsigned short)((x + 0x7fffu + ((x >> 16) & 1u)) >> 16);
}
__device__ __forceinline__ unsigned int cvtpk(float lo, float hi) {
    unsigned int r;
    asm("v_cvt_pk_bf16_f32 %0, %1, %2" : "=v"(r) : "v"(lo), "v"(hi));
    return r;
}

// ---------- 24->24 stride-2 conv step, LDS -> LDS, NHWC, WAVE-uniform channel split ----------
template<int NCO>
__device__ __forceinline__ void convs24_wave(const unsigned short* __restrict__ in, int H,
                                             unsigned short* __restrict__ out, int OH,
                                             const float* __restrict__ wc, const float* __restrict__ bias,
                                             const float* __restrict__ bng, const float* __restrict__ bnb,
                                             int wid, int lane, int nw)
{
    const int per = 24 / NCO;
    int npix = OH * OH;
    int nchunk = (npix + 63) >> 6;
    int ntask = nchunk * per;
    for (int wt = wid; wt < ntask; wt += nw) {
        int sc = wt % per;
        int chunk = wt / per;
        int co0 = __builtin_amdgcn_readfirstlane(sc * NCO);
        int p = chunk * 64 + lane;
        bool act = p < npix;
        int pc = act ? p : npix - 1;
        int ow = pc % OH, oh = pc / OH;
        float acc[NCO];
        #pragma unroll
        for (int c = 0; c < NCO; ++c) acc[c] = 0.f;
        int ih0 = 2 * oh - 1, iw0 = 2 * ow - 1;
        #pragma unroll 1
        for (int ky = 0; ky < 3; ++ky) {
            int ih = ih0 + ky; if (ih < 0) continue;
            #pragma unroll 1
            for (int kx = 0; kx < 3; ++kx) {
                int iw = iw0 + kx; if (iw < 0) continue;
                const unsigned short* pp = in + (ih * H + iw) * 24;
                u16x4 v[6];
                #pragma unroll
                for (int m = 0; m < 6; ++m) v[m] = *(const u16x4*)(pp + m * 4);
                float x[24];
                #pragma unroll
                for (int m = 0; m < 6; ++m)
                    #pragma unroll
                    for (int e = 0; e < 4; ++e) x[m * 4 + e] = bf2f(v[m][e]);
                int kb = ky * 3 + kx;
                const float* wk = wc + kb * 576 + co0;
                #pragma unroll
                for (int ci = 0; ci < 24; ++ci) {
                    float xv = x[ci];
                    #pragma unroll
                    for (int c = 0; c < NCO; ++c)
                        acc[c] += xv * wk[ci * 24 + c];      // wave-uniform s_load
                }
            }
        }
        if (act) {
            unsigned short* op = out + p * 24 + co0;
            #pragma unroll
            for (int c4i = 0; c4i < NCO / 4; ++c4i) {
                u16x4 o;
                #pragma unroll
                for (int e = 0; e < 4; ++e) {
                    int co = co0 + c4i * 4 + e;
                    float scale = bng[co] * 0.9999950000374997f;
                    o[e] = f2bf((acc[c4i * 4 + e] + bias[co]) * scale + bnb[co]);
                }
                *(u16x4*)(op + c4i * 4) = o;
            }
        }
    }
}

// ---------- fully fused conv1..conv4: one block per image; writes only Xf ----------
__global__ __launch_bounds__(1024) void conv_fused_kernel(
    const float* __restrict__ im,
    const float* __restrict__ wc1, const float* __restrict__ c1b,
    const float* __restrict__ n1g, const float* __restrict__ n1b,
    const float* __restrict__ wc2, const float* __restrict__ c2b,
    const float* __restrict__ n2g, const float* __restrict__ n2b,
    const float* __restrict__ wc3, const float* __restrict__ c3b,
    const float* __restrict__ n3g, const float* __restrict__ n3b,
    const float* __restrict__ wc4, const float* __restrict__ c4b,
    const float* __restrict__ n4g, const float* __restrict__ n4b,
    unsigned short* __restrict__ Xf)
{
    extern __shared__ unsigned short smem[];
    unsigned short* bufA = smem;
    unsigned short* bufB = smem + 19200;
    int b = blockIdx.x, t = threadIdx.x;

    const float* ip = im + (size_t)b * 19200;
    for (int i = t; i < 19200; i += 1024) bufA[i] = f2bf(ip[i]);
    __syncthreads();

    for (int p = t; p < 1600; p += 1024) {
        int ow = p % 40, oh = p / 40;
        float acc[24];
        #pragma unroll
        for (int co = 0; co < 24; ++co) acc[co] = 0.f;
        int ih0 = 2 * oh - 1, iw0 = 2 * ow - 1;
        #pragma unroll 1
        for (int ci = 0; ci < 3; ++ci) {
            #pragma unroll 1
            for (int ky = 0; ky < 3; ++ky) {
                int ih = ih0 + ky; if (ih < 0) continue;
                #pragma unroll 1
                for (int kx = 0; kx < 3; ++kx) {
                    int iw = iw0 + kx; if (iw < 0) continue;
                    float x = bf2f(bufA[ci * 6400 + ih * 80 + iw]);
                    const float* wk = wc1 + (ci * 9 + ky * 3 + kx) * 24;
                    #pragma unroll
                    for (int co = 0; co < 24; ++co) acc[co] += x * wk[co];
                }
            }
        }
        unsigned short* op = bufB + p * 24;
        u16x4 o[6];
        #pragma unroll
        for (int co = 0; co < 24; ++co) {
            float scale = n1g[co] * 0.9999950000374997f;
            o[co >> 2][co & 3] = f2bf((acc[co] + c1b[co]) * scale + n1b[co]);
        }
        #pragma unroll
        for (int m = 0; m < 6; ++m) *(u16x4*)(op + m * 4) = o[m];
    }
    __syncthreads();

    int wid = t >> 6, lane = t & 63;

    convs24_wave<12>(bufB, 40, bufA, 20, wc2, c2b, n2g, n2b, wid, lane, 16);
    __syncthreads();
    convs24_wave<8>(bufA, 20, bufB, 10, wc3, c3b, n3g, n3b, wid, lane, 16);
    __syncthreads();

    for (int wt = wid; wt < 3; wt += 16) {
        int co0 = __builtin_amdgcn_readfirstlane(wt * 8);
        int p = lane;
        bool act = p < 25;
        int pc = act ? p : 24;
        int ow = pc % 5, oh = pc / 5;
        float acc[8];
        #pragma unroll
        for (int c = 0; c < 8; ++c) acc[c] = 0.f;
        int ih0 = 2 * oh - 1, iw0 = 2 * ow - 1;
        #pragma unroll 1
        for (int ky = 0; ky < 3; ++ky) {
            int ih = ih0 + ky; if (ih < 0) continue;
            #pragma unroll 1
            for (int kx = 0; kx < 3; ++kx) {
                int iw = iw0 + kx; if (iw < 0) continue;
                const unsigned short* pp = bufB + (ih * 10 + iw) * 24;
                u16x4 v[6];
                #pragma unroll
                for (int m = 0; m < 6; ++m) v[m] = *(const u16x4*)(pp + m * 4);
                float x[24];
                #pragma unroll
                for (int m = 0; m < 6; ++m)
                    #pragma unroll
                    for (int e = 0; e < 4; ++e) x[m * 4 + e] = bf2f(v[m][e]);
                int kb = ky * 3 + kx;
                const float* wk = wc4 + kb * 576 + co0;
                #pragma unroll
                for (int ci = 0; ci < 24; ++ci) {
                    float xv = x[ci];
                    #pragma unroll
                    for (int c = 0; c < 8; ++c)
                        acc[c] += xv * wk[ci * 24 + c];
                }
            }
        }
        if (act) {
            unsigned short* op = Xf + ((size_t)b * 25 + p) * 32 + co0;
            #pragma unroll
            for (int c4i = 0; c4i < 2; ++c4i) {
                u16x4 o;
                #pragma unroll
                for (int e = 0; e < 4; ++e) {
                    int co = co0 + c4i * 4 + e;
                    float scale = n4g[co] * 0.9999950000374997f;
                    o[e] = f2bf((acc[c4i * 4 + e] + c4b[co]) * scale + n4b[co]);
                }
                *(u16x4*)(op + c4i * 4) = o;
            }
            if (co0 == 0) {
                u16x8 o;
                o[0] = f2bf((oh - 2) * 0.5f);
                o[1] = f2bf((ow - 2) * 0.5f);
                #pragma unroll
                for (int e = 2; e < 8; ++e) o[e] = 0;
                *(u16x8*)(Xf + ((size_t)b * 25 + p) * 32 + 24) = o;
            }
        }
    }
}

// ---------- prep_misc ----------
__global__ void prep_misc_kernel(const float* __restrict__ g1w, const float* __restrict__ g1b,
                                 const float* __restrict__ g2w, const float* __restrict__ g3w,
                                 const float* __restrict__ g4w, const float* __restrict__ f1w,
                                 const float* __restrict__ f2w, const float* __restrict__ f3w,
                                 const float* __restrict__ q,
                                 const float* __restrict__ c1w, const float* __restrict__ c2w,
                                 const float* __restrict__ c3w, const float* __restrict__ c4w,
                                 unsigned short* __restrict__ W1t,
                                 unsigned short* __restrict__ wg2, unsigned short* __restrict__ wg3,
                                 unsigned short* __restrict__ wg4, unsigned short* __restrict__ wf1,
                                 unsigned short* __restrict__ wf2, unsigned short* __restrict__ wt3,
                                 float* __restrict__ xg, float* __restrict__ Cq,
                                 float* __restrict__ wc1, float* __restrict__ wc2,
                                 float* __restrict__ wc3, float* __restrict__ wc4)
{
    int blk = blockIdx.x, t = threadIdx.x;
    if (blk < 64) {
        int i = blk * 256 + t;
        int u = i >> 5, k = i & 31;
        float v = 0.f;
        if (k < 26) v = (u < 256) ? g1w[u * 63 + k] : g1w[(u - 256) * 63 + 26 + k];
        W1t[i] = f2bf(v);
    } else if (blk < 1344) {
        int s = blk - 64;
        int which = s >> 8;
        int i = (s & 255) * 256 + t;
        int kin = i & 31, u = (i >> 5) & 255, kk = i >> 13;
        const float* w = (which == 0) ? g2w : (which == 1) ? g3w :
                         (which == 2) ? g4w : (which == 3) ? f1w : f2w;
        unsigned short* wt = (which == 0) ? wg2 : (which == 1) ? wg3 :
                             (which == 2) ? wg4 : (which == 3) ? wf1 : wf2;
        wt[i] = f2bf(w[u * 256 + kk * 32 + kin]);
    } else if (blk < 1360) {
        int i = (blk - 1344) * 256 + t;
        int kin = i & 31, u = (i >> 5) & 15, kk = i >> 9;
        wt3[i] = (u < 10) ? f2bf(f3w[u * 256 + kk * 32 + kin]) : 0;
    } else if (blk < 1872) {
        xg[(size_t)(blk - 1360) * 256 + t] = 0.f;
    } else if (blk < 2384) {
        int b = blk - 1872, u = t;
        float acc = g1b[u];
        #pragma unroll
        for (int k = 0; k < 11; ++k)
            acc += g1w[u * 63 + 52 + k] * q[b * 11 + k];
        Cq[(size_t)b * 256 + u] = acc;
    } else {
        int i = (blk - 2384) * 256 + t;
        if (i < 648) {
            int k = i / 24, co = i % 24;
            wc1[i] = c1w[co * 27 + k];
        } else if (i < 16200) {
            int j = i - 648;
            int which = j / 5184; j %= 5184;
            int kb = j / 576, r = j % 576, ci = r / 24, co = r % 24;
            const float* src = (which == 0) ? c2w : (which == 1) ? c3w : c4w;
            float* dst = (which == 0) ? wc2 : (which == 1) ? wc3 : wc4;
            dst[j] = src[co * 216 + ci * 9 + kb];
        }
    }
}

// ---------- prep GEMM (swapped output): Xf[12800x32] x W1t -> A(+Cq), Bv ----------
// mfma(bf, af): D-row = W1t row (u), D-col = Xf row. Lane holds 4 consecutive u
// per Xf-row -> 8B stores instead of 2B scatter.
__global__ __launch_bounds__(512) void prep_gemm_kernel(
    const unsigned short* __restrict__ Xf, const unsigned short* __restrict__ W1t,
    const float* __restrict__ Cq,
    unsigned short* __restrict__ A, unsigned short* __restrict__ Bv)
{
    int t = threadIdx.x, w8 = t >> 6, lane = t & 63;
    int rg = w8 & 3, cg = w8 >> 2;          // rg: 16-row group of Xf; cg: 0->A, 1->Bv
    int lr = lane & 15, lh = lane >> 4;
    int xrow = blockIdx.x * 64 + rg * 16 + lr;
    bf16x8 af = *(const bf16x8*)(Xf + (size_t)xrow * 32 + lh * 8);
    int b = xrow / 25;
    unsigned short* dst = (cg == 0) ? A : Bv;
    #pragma unroll
    for (int ct = 0; ct < 16; ++ct) {
        bf16x8 bf = *(const bf16x8*)(W1t + (size_t)(cg * 256 + ct * 16 + lr) * 32 + lh * 8);
        f32x4 acc = __builtin_amdgcn_mfma_f32_16x16x32_bf16(bf, af, (f32x4){0.f,0.f,0.f,0.f}, 0, 0, 0);
        int u0 = ct * 16 + lh * 4;
        if (cg == 0) {
            f32x4 cqv = *(const f32x4*)(Cq + (size_t)b * 256 + u0);
            acc[0] += cqv[0]; acc[1] += cqv[1]; acc[2] += cqv[2]; acc[3] += cqv[3];
        }
        unsigned int w0 = cvtpk(acc[0], acc[1]), w1 = cvtpk(acc[2], acc[3]);
        unsigned int* dp = (unsigned int*)(dst + (size_t)xrow * 256 + u0);
        dp[0] = w0; dp[1] = w1;
    }
}

// ---------- gemm over 128 rows: wave = 128 rows x 64 cols ----------
template<bool SWAP>
__device__ __forceinline__ void gemm_k128(const unsigned short* __restrict__ W,
                                          const unsigned short* X,
                                          int lr, int lh, int wc, f32x4 acc[8][4])
{
    bf16x8 bcur[4], bnxt[4];
    #pragma unroll
    for (int cb = 0; cb < 4; ++cb)
        bcur[cb] = *(const bf16x8*)(W + (wc + cb * 16 + lr) * 32 + lh * 8);
    #pragma unroll
    for (int kk = 0; kk < 8; ++kk) {
        if (kk < 7) {
            #pragma unroll
            for (int cb = 0; cb < 4; ++cb)
                bnxt[cb] = *(const bf16x8*)(W + (size_t)(kk + 1) * 8192 + (wc + cb * 16 + lr) * 32 + lh * 8);
        }
        #pragma unroll
        for (int rb = 0; rb < 8; ++rb) {
            int row = rb * 16 + lr;
            int sg = (kk * 4 + lh) ^ (row & 15);
            bf16x8 af = *(const bf16x8*)(X + row * 256 + sg * 8);
            #pragma unroll
            for (int cb = 0; cb < 4; ++cb)
                acc[rb][cb] = SWAP
                    ? __builtin_amdgcn_mfma_f32_16x16x32_bf16(bcur[cb], af, acc[rb][cb], 0, 0, 0)
                    : __builtin_amdgcn_mfma_f32_16x16x32_bf16(af, bcur[cb], acc[rb][cb], 0, 0, 0);
        }
        #pragma unroll
        for (int cb = 0; cb < 4; ++cb) bcur[cb] = bnxt[cb];
    }
}

// ---------- gemm over 64 rows (fc) ----------
template<bool SWAP>
__device__ __forceinline__ void gemm_k64(const unsigned short* __restrict__ W,
                                         const unsigned short* X,
                                         int lr, int lh, int wc, f32x4 acc[4][4])
{
    bf16x8 bcur[4], bnxt[4];
    #pragma unroll
    for (int cb = 0; cb < 4; ++cb)
        bcur[cb] = *(const bf16x8*)(W + (wc + cb * 16 + lr) * 32 + lh * 8);
    #pragma unroll
    for (int kk = 0; kk < 8; ++kk) {
        if (kk < 7) {
            #pragma unroll
            for (int cb = 0; cb < 4; ++cb)
                bnxt[cb] = *(const bf16x8*)(W + (size_t)(kk + 1) * 8192 + (wc + cb * 16 + lr) * 32 + lh * 8);
        }
        #pragma unroll
        for (int rb = 0; rb < 4; ++rb) {
            int row = rb * 16 + lr;
            int sg = (kk * 4 + lh) ^ (row & 15);
            bf16x8 af = *(const bf16x8*)(X + row * 256 + sg * 8);
            #pragma unroll
            for (int cb = 0; cb < 4; ++cb)
                acc[rb][cb] = SWAP
                    ? __builtin_amdgcn_mfma_f32_16x16x32_bf16(bcur[cb], af, acc[rb][cb], 0, 0, 0)
                    : __builtin_amdgcn_mfma_f32_16x16x32_bf16(af, bcur[cb], acc[rb][cb], 0, 0, 0);
        }
        #pragma unroll
        for (int cb = 0; cb < 4; ++cb) bcur[cb] = bnxt[cb];
    }
}

// ---------- fused g2/g3/g4 + pair-sum; 128-row tile; XCD-grouped blocks ----------
__global__ __launch_bounds__(256, 2) void gmlp_kernel(
    const unsigned short* __restrict__ A, const unsigned short* __restrict__ Bv,
    const unsigned short* __restrict__ w2, const float* __restrict__ b2,
    const unsigned short* __restrict__ w3, const float* __restrict__ b3,
    const unsigned short* __restrict__ w4, const float* __restrict__ b4,
    float* __restrict__ xg)
{
    __shared__ unsigned short X[128 * 256];   // 64 KB

    // bijective XCD swizzle (m204): grid 2560, 8 XCDs, q = 320.
    // HW maps orig%8 -> XCD; this puts logical blocks 0..319 (b = 0..63) on XCD0 etc.
    int orig = blockIdx.x;
    int blk  = (orig & 7) * 320 + (orig >> 3);
    int b    = blk / 5;
    int tile = blk % 5;
    int row0 = tile * 128;
    int t = threadIdx.x;

    {
        int r = t >> 1, half = t & 1;
        int prow = row0 + r;
        if (prow < 625) {
            int i = prow / 25, j = prow % 25;
            const unsigned short* Ap = A  + ((size_t)b * 25 + j) * 256;
            const unsigned short* Bp = Bv + ((size_t)b * 25 + i) * 256;
            #pragma unroll
            for (int k = 0; k < 16; ++k) {
                int g = half + 2 * k;
                int c0 = g * 8;
                u16x8 av = *(const u16x8*)(Ap + c0);
                u16x8 bv = *(const u16x8*)(Bp + c0);
                float v[8];
                #pragma unroll
                for (int e = 0; e < 8; ++e)
                    v[e] = fmaxf(bf2f(av[e]) + bf2f(bv[e]), 0.f);
                u32x4 o = { cvtpk(v[0], v[1]), cvtpk(v[2], v[3]),
                            cvtpk(v[4], v[5]), cvtpk(v[6], v[7]) };
                int sg = g ^ (r & 15);
                *(u32x4*)(X + r * 256 + sg * 8) = o;
            }
        } else {
            u32x4 z = {0, 0, 0, 0};
            #pragma unroll
            for (int k = 0; k < 16; ++k) {
                int g = half + 2 * k;
                int sg = g ^ (r & 15);
                *(u32x4*)(X + r * 256 + sg * 8) = z;
            }
        }
    }
    __syncthreads();

    int wid = t >> 6, lane = t & 63;
    int wc = wid * 64;
    int lr = lane & 15, lh = lane >> 4;

    const unsigned short* Wsw[2] = { w2, w3 };
    const float* Bsw[2] = { b2, b3 };
    #pragma unroll 1
    for (int L = 0; L < 2; ++L) {
        f32x4 acc[8][4];
        #pragma unroll
        for (int rb = 0; rb < 8; ++rb)
            #pragma unroll
            for (int cb = 0; cb < 4; ++cb) acc[rb][cb] = (f32x4){0.f,0.f,0.f,0.f};
        gemm_k128<true>(Wsw[L], X, lr, lh, wc, acc);

        f32x4 bsw[4];
        #pragma unroll
        for (int cb = 0; cb < 4; ++cb)
            bsw[cb] = *(const f32x4*)(Bsw[L] + wc + cb * 16 + lh * 4);

        __syncthreads();
        #pragma unroll
        for (int rb = 0; rb < 8; ++rb) {
            int prow = rb * 16 + lr;
            #pragma unroll
            for (int cb = 0; cb < 4; ++cb) {
                float v0 = fmaxf(acc[rb][cb][0] + bsw[cb][0], 0.f);
                float v1 = fmaxf(acc[rb][cb][1] + bsw[cb][1], 0.f);
                float v2 = fmaxf(acc[rb][cb][2] + bsw[cb][2], 0.f);
                float v3 = fmaxf(acc[rb][cb][3] + bsw[cb][3], 0.f);
                unsigned int w0 = cvtpk(v0, v1), w1 = cvtpk(v2, v3);
                int u0 = wc + cb * 16 + lh * 4;
                int sg = (u0 >> 3) ^ (prow & 15);
                unsigned int* dst = (unsigned int*)(X + prow * 256 + sg * 8 + (u0 & 7));
                dst[0] = w0; dst[1] = w1;
            }
        }
        __syncthreads();
    }

    {
        f32x4 acc[8][4];
        #pragma unroll
        for (int rb = 0; rb < 8; ++rb)
            #pragma unroll
            for (int cb = 0; cb < 4; ++cb) acc[rb][cb] = (f32x4){0.f,0.f,0.f,0.f};
        gemm_k128<false>(w4, X, lr, lh, wc, acc);

        float bias[4];
        #pragma unroll
        for (int cb = 0; cb < 4; ++cb) bias[cb] = b4[wc + cb * 16 + lr];

        float csum[4] = {0.f, 0.f, 0.f, 0.f};
        #pragma unroll
        for (int rb = 0; rb < 8; ++rb) {
            #pragma unroll
            for (int reg = 0; reg < 4; ++reg) {
                int rowloc = rb * 16 + lh * 4 + reg;
                bool valid = (row0 + rowloc) < 625;
                #pragma unroll
                for (int cb = 0; cb < 4; ++cb) {
                    float v = fmaxf(acc[rb][cb][reg] + bias[cb], 0.f);
                    if (valid) csum[cb] += v;
                }
            }
        }
        #pragma unroll
        for (int cb = 0; cb < 4; ++cb) {
            csum[cb] += __shfl_xor(csum[cb], 16);
            csum[cb] += __shfl_xor(csum[cb], 32);
        }
        if (lh == 0) {
            #pragma unroll
            for (int cb = 0; cb < 4; ++cb)
                atomicAdd(&xg[(size_t)b * 256 + wc + cb * 16 + lr], csum[cb]);
        }
    }
}

// ---------- fc via MFMA ----------
__global__ __launch_bounds__(256) void fc_mfma_kernel(
    const float* __restrict__ xg,
    const unsigned short* __restrict__ wf1, const float* __restrict__ f1b,
    const unsigned short* __restrict__ wf2, const float* __restrict__ f2b,
    const unsigned short* __restrict__ wt3, const float* __restrict__ f3b,
    float* __restrict__ out)
{
    __shared__ unsigned short X[64 * 256];   // 32 KB
    int r0 = blockIdx.x * 64;
    int t = threadIdx.x;

    {
        int r = t >> 2, quad = t & 3;
        const float* Sp = xg + (size_t)(r0 + r) * 256;
        #pragma unroll
        for (int k = 0; k < 8; ++k) {
            int g = quad + 4 * k;
            int c0 = g * 8;
            f32x4 a0 = *(const f32x4*)(Sp + c0);
            f32x4 a1 = *(const f32x4*)(Sp + c0 + 4);
            u32x4 o = { cvtpk(a0[0], a0[1]), cvtpk(a0[2], a0[3]),
                        cvtpk(a1[0], a1[1]), cvtpk(a1[2], a1[3]) };
            int sg = g ^ (r & 15);
            *(u32x4*)(X + r * 256 + sg * 8) = o;
        }
    }
    __syncthreads();

    int wid = t >> 6, lane = t & 63;
    int wc = wid * 64;
    int lr = lane & 15, lh = lane >> 4;

    const unsigned short* Ws[2] = { wf1, wf2 };
    const float* Bs[2] = { f1b, f2b };
    #pragma unroll 1
    for (int L = 0; L < 2; ++L) {
        f32x4 acc[4][4];
        #pragma unroll
        for (int rb = 0; rb < 4; ++rb)
            #pragma unroll
            for (int cb = 0; cb < 4; ++cb) acc[rb][cb] = (f32x4){0.f,0.f,0.f,0.f};
        gemm_k64<true>(Ws[L], X, lr, lh, wc, acc);

        f32x4 bsw[4];
        #pragma unroll
        for (int cb = 0; cb < 4; ++cb)
            bsw[cb] = *(const f32x4*)(Bs[L] + wc + cb * 16 + lh * 4);

        __syncthreads();
        #pragma unroll
        for (int rb = 0; rb < 4; ++rb) {
            int prow = rb * 16 + lr;
            #pragma unroll
            for (int cb = 0; cb < 4; ++cb) {
                float v0 = fmaxf(acc[rb][cb][0] + bsw[cb][0], 0.f);
                float v1 = fmaxf(acc[rb][cb][1] + bsw[cb][1], 0.f);
                float v2 = fmaxf(acc[rb][cb][2] + bsw[cb][2], 0.f);
                float v3 = fmaxf(acc[rb][cb][3] + bsw[cb][3], 0.f);
                unsigned int w0 = cvtpk(v0, v1), w1 = cvtpk(v2, v3);
                int u0 = wc + cb * 16 + lh * 4;
                int sg = (u0 >> 3) ^ (prow & 15);
                unsigned int* dst = (unsigned int*)(X + prow * 256 + sg * 8 + (u0 & 7));
                dst[0] = w0; dst[1] = w1;
            }
        }
        __syncthreads();
    }

    if (wid == 0) {
        f32x4 acc3[4];
        #pragma unroll
        for (int rb = 0; rb < 4; ++rb) acc3[rb] = (f32x4){0.f,0.f,0.f,0.f};
        #pragma unroll
        for (int kk = 0; kk < 8; ++kk) {
            bf16x8 wfrag = *(const bf16x8*)(wt3 + (size_t)kk * 512 + lr * 32 + lh * 8);
            #pragma unroll
            for (int rb = 0; rb < 4; ++rb) {
                int row = rb * 16 + lr;
                int sg = (kk * 4 + lh) ^ (row & 15);
                bf16x8 af = *(const bf16x8*)(X + row * 256 + sg * 8);
                acc3[rb] = __builtin_amdgcn_mfma_f32_16x16x32_bf16(wfrag, af, acc3[rb], 0, 0, 0);
            }
        }
        #pragma unroll
        for (int rb = 0; rb < 4; ++rb) {
            int prow = rb * 16 + lr;
            #pragma unroll
            for (int reg = 0; reg < 4; ++reg) {
                int u = lh * 4 + reg;
                if (u < 10) out[(size_t)(r0 + prow) * 10 + u] = acc3[rb][reg] + f3b[u];
            }
        }
    }
}

// ---------- launch ----------
extern "C" void kernel_launch(void* const* d_in, const int* in_sizes, int n_in,
                              void* d_out, int out_size, void* d_ws, size_t ws_size,
                              hipStream_t stream)
{
    const float* im  = (const float*)d_in[0];
    const float* q   = (const float*)d_in[1];
    const float* c1w = (const float*)d_in[2];
    const float* c1b = (const float*)d_in[3];
    const float* n1g = (const float*)d_in[4];
    const float* n1b = (const float*)d_in[5];
    const float* c2w = (const float*)d_in[6];
    const float* c2b = (const float*)d_in[7];
    const float* n2g = (const float*)d_in[8];
    const float* n2b = (const float*)d_in[9];
    const float* c3w = (const float*)d_in[10];
    const float* c3b = (const float*)d_in[11];
    const float* n3g = (const float*)d_in[12];
    const float* n3b = (const float*)d_in[13];
    const float* c4w = (const float*)d_in[14];
    const float* c4b = (const float*)d_in[15];
    const float* n4g = (const float*)d_in[16];
    const float* n4b = (const float*)d_in[17];
    const float* g1w = (const float*)d_in[18];
    const float* g1b = (const float*)d_in[19];
    const float* g2w = (const float*)d_in[20];
    const float* g2b = (const float*)d_in[21];
    const float* g3w = (const float*)d_in[22];
    const float* g3b = (const float*)d_in[23];
    const float* g4w = (const float*)d_in[24];
    const float* g4b = (const float*)d_in[25];
    const float* f1w = (const float*)d_in[26];
    const float* f1b = (const float*)d_in[27];
    const float* f2w = (const float*)d_in[28];
    const float* f2b = (const float*)d_in[29];
    const float* f3w = (const float*)d_in[30];
    const float* f3b = (const float*)d_in[31];

    char* ws = (char*)d_ws;
    size_t off = 0;
    auto alloc = [&](size_t bytes) -> void* {
        void* p = ws + off;
        off += (bytes + 255) & ~(size_t)255;
        return p;
    };
    unsigned short* A   = (unsigned short*)alloc(3276800ull * 2);
    unsigned short* Bv  = (unsigned short*)alloc(3276800ull * 2);
    unsigned short* Xf  = (unsigned short*)alloc(409600ull * 2);
    unsigned short* W1t = (unsigned short*)alloc(16384ull * 2);
    unsigned short* wg2 = (unsigned short*)alloc(65536ull * 2);
    unsigned short* wg3 = (unsigned short*)alloc(65536ull * 2);
    unsigned short* wg4 = (unsigned short*)alloc(65536ull * 2);
    unsigned short* wf1 = (unsigned short*)alloc(65536ull * 2);
    unsigned short* wf2 = (unsigned short*)alloc(65536ull * 2);
    unsigned short* wt3 = (unsigned short*)alloc(4096ull * 2);
    float* Cq  = (float*)alloc(131072ull * 4);
    float* xg  = (float*)alloc(131072ull * 4);
    float* wc1 = (float*)alloc(648ull * 4);
    float* wc2 = (float*)alloc(5184ull * 4);
    float* wc3 = (float*)alloc(5184ull * 4);
    float* wc4 = (float*)alloc(5184ull * 4);

    prep_misc_kernel<<<2448, 256, 0, stream>>>(g1w, g1b, g2w, g3w, g4w, f1w, f2w, f3w, q,
                                               c1w, c2w, c3w, c4w,
                                               W1t, wg2, wg3, wg4, wf1, wf2, wt3, xg, Cq,
                                               wc1, wc2, wc3, wc4);

    conv_fused_kernel<<<512, 1024, 115200, stream>>>(im,
        wc1, c1b, n1g, n1b, wc2, c2b, n2g, n2b,
        wc3, c3b, n3g, n3b, wc4, c4b, n4g, n4b, Xf);

    prep_gemm_kernel<<<200, 512, 0, stream>>>(Xf, W1t, Cq, A, Bv);

    gmlp_kernel<<<512 * 5, 256, 0, stream>>>(A, Bv, wg2, g2b, wg3, g3b, wg4, g4b, xg);

    fc_mfma_kernel<<<8, 256, 0, stream>>>(xg, wf1, f1b, wf2, f2b, wt3, f3b, (float*)d_out);
}